// Round 3
// baseline (1186.452 us; speedup 1.0000x reference)
//
#include <hip/hip_runtime.h>
#include <hip/hip_bf16.h>

// ---------- conv 3x3 stride2 pad1 + relu ----------
__global__ __launch_bounds__(256) void k_conv_s2(const float* __restrict__ in, const float* __restrict__ w,
    const float* __restrict__ bias, float* __restrict__ out,
    int Cin, int Hin, int Win, int Cout, int Hout, int Wout){
  int idx = blockIdx.x*256 + threadIdx.x;
  int total = Cout*Hout*Wout;
  if(idx >= total) return;
  int ox = idx % Wout; int t = idx / Wout; int oy = t % Hout; int oc = t / Hout;
  float acc = bias[oc];
  int iy0 = oy*2 - 1, ix0 = ox*2 - 1;
  for(int ic=0; ic<Cin; ++ic){
    const float* ip = in + ic*Hin*Win;
    const float* wp = w + (oc*Cin + ic)*9;
    #pragma unroll
    for(int ky=0; ky<3; ++ky){
      int iy = iy0 + ky;
      if((unsigned)iy >= (unsigned)Hin) continue;
      const float* row = ip + iy*Win;
      #pragma unroll
      for(int kx=0; kx<3; ++kx){
        int ix = ix0 + kx;
        if((unsigned)ix < (unsigned)Win) acc += row[ix] * wp[ky*3+kx];
      }
    }
  }
  out[idx] = fmaxf(acc, 0.f);
}

// ---------- q/k/v projections ----------
template<int C, int O>
__global__ __launch_bounds__(256) void k_qkv(const float* __restrict__ x,  // [C][N]
    const float* __restrict__ wq, const float* __restrict__ bq,
    const float* __restrict__ wk, const float* __restrict__ bk,
    const float* __restrict__ wv, const float* __restrict__ bv,
    float* __restrict__ q,  // [N][O]
    float* __restrict__ k,  // [O][N]
    float* __restrict__ v,  // [C][N]
    int N){
  int n = blockIdx.x*256 + threadIdx.x;
  if(n >= N) return;
  float xc[C];
  #pragma unroll
  for(int c=0;c<C;++c) xc[c] = x[c*N+n];
  #pragma unroll
  for(int o=0;o<O;++o){
    float aq = bq[o], ak = bk[o];
    #pragma unroll
    for(int c=0;c<C;++c){ aq += wq[o*C+c]*xc[c]; ak += wk[o*C+c]*xc[c]; }
    q[n*O+o] = aq;
    k[o*N+n] = ak;
  }
  for(int o=0;o<C;++o){
    float av = bv[o];
    #pragma unroll
    for(int c=0;c<C;++c) av += wv[o*C+c]*xc[c];
    v[o*N+n] = av;
  }
}

// ---------- flash-style attention + residual ----------
// TPQ threads per query split the key range; K/V tiles staged in LDS;
// float4 LDS reads (4 keys / iter); butterfly shuffle combine. out = gamma*att + xin.
template<int C, int O, int TPQ, int TN>
__global__ __launch_bounds__(256) void k_attn(const float* __restrict__ q, const float* __restrict__ kk,
    const float* __restrict__ v, const float* __restrict__ xin,
    const float* __restrict__ gamma, float* __restrict__ out, int N){
  constexpr int QPB = 256/TPQ;
  __shared__ float4 svbuf[C*TN/4];
  __shared__ float4 skbuf[TN*O/4];
  float* sk = (float*)skbuf;
  const float4* sv4 = (const float4*)svbuf;
  const int tid = threadIdx.x;
  const int qi = tid / TPQ, si = tid % TPQ;
  const int m = blockIdx.x*QPB + qi;
  float qv[O];
  #pragma unroll
  for(int o=0;o<O;++o) qv[o] = q[m*O+o];
  float acc[C];
  #pragma unroll
  for(int c=0;c<C;++c) acc[c] = 0.f;
  float den = 0.f;
  const float4* v4 = (const float4*)v;
  for(int n0=0; n0<N; n0+=TN){
    __syncthreads();
    for(int i=tid; i<TN*O; i+=256){
      int o = i / TN, j = i % TN;
      sk[j*O+o] = kk[o*N + n0 + j];          // [j][o] layout for float4 score reads
    }
    for(int i=tid; i<C*TN/4; i+=256){
      svbuf[i] = v4[(i/(TN/4))*(N/4) + n0/4 + (i%(TN/4))];   // [c][j] layout
    }
    __syncthreads();
    for(int jq=si; jq<TN/4; jq+=TPQ){
      int j = jq*4;
      float p[4];
      #pragma unroll
      for(int u=0;u<4;++u){
        float s = 0.f;
        const float4* kp = (const float4*)(&sk[(j+u)*O]);
        #pragma unroll
        for(int o4=0;o4<O/4;++o4){
          float4 k4 = kp[o4];
          s += qv[o4*4+0]*k4.x + qv[o4*4+1]*k4.y + qv[o4*4+2]*k4.z + qv[o4*4+3]*k4.w;
        }
        p[u] = __expf(s);          // scores are O(1): safe without max-subtraction
        den += p[u];
      }
      #pragma unroll
      for(int c=0;c<C;++c){
        float4 vv = sv4[c*(TN/4)+jq];
        acc[c] += p[0]*vv.x + p[1]*vv.y + p[2]*vv.z + p[3]*vv.w;
      }
    }
  }
  #pragma unroll
  for(int off=1; off<TPQ; off<<=1){
    den += __shfl_xor(den, off);
    #pragma unroll
    for(int c=0;c<C;++c) acc[c] += __shfl_xor(acc[c], off);
  }
  const float g = gamma[0] / den;
  for(int c=si; c<C; c+=TPQ)
    out[c*N+m] = acc[c]*g + xin[c*N+m];
}

// ---------- fc_mu / fc_lv partial sums (chunk of 256 features per block) ----------
__global__ __launch_bounds__(128) void k_fc2_part(const float* __restrict__ hf,
    const float* __restrict__ wmu, const float* __restrict__ wlv,
    float* __restrict__ pmu, float* __restrict__ plv){
  __shared__ float sh[256];
  const int t = threadIdx.x;
  const int f0 = blockIdx.x * 256;
  for(int i=t; i<256; i+=128) sh[i] = hf[f0+i];
  __syncthreads();
  float a0=0.f, a1=0.f, c0=0.f, c1=0.f;
  const float2* wm = (const float2*)wmu + (size_t)f0*128 + t;   // 128 float2 per row of 256
  const float2* wl = (const float2*)wlv + (size_t)f0*128 + t;
  for(int j=0;j<256;++j){
    float h = sh[j];
    float2 um = wm[(size_t)j*128];
    float2 ul = wl[(size_t)j*128];
    a0 += h*um.x; a1 += h*um.y;
    c0 += h*ul.x; c1 += h*ul.y;
  }
  pmu[blockIdx.x*256 + 2*t]   = a0;
  pmu[blockIdx.x*256 + 2*t+1] = a1;
  plv[blockIdx.x*256 + 2*t]   = c0;
  plv[blockIdx.x*256 + 2*t+1] = c1;
}

// ---------- reduce partials + bias + reparametrize; emit mu/logvar (f32) ----------
__global__ __launch_bounds__(256) void k_reparam(const float* __restrict__ pmu, const float* __restrict__ plv,
    const float* __restrict__ bmu, const float* __restrict__ blv, const float* __restrict__ eps,
    float* __restrict__ z, float* __restrict__ omu, float* __restrict__ olv){
  const int o = threadIdx.x;
  float mu = bmu[o], lv = blv[o];
  for(int i=0;i<392;++i){ mu += pmu[i*256+o]; lv += plv[i*256+o]; }
  float zz = mu + eps[o] * expf(0.5f*lv);
  z[o] = zz;
  omu[o] = mu;
  olv[o] = lv;
}

// ---------- decoder fc: d = relu(z @ W + b), W [256][100352] ----------
__global__ __launch_bounds__(256) void k_fc_dec(const float* __restrict__ z, const float* __restrict__ w,
    const float* __restrict__ b, float* __restrict__ out){
  __shared__ float sz[256];
  const int t = threadIdx.x;
  sz[t] = z[t];
  __syncthreads();
  const int f2 = blockIdx.x*256 + t;   // pair index; FLAT/2 = 50176
  float a0 = b[2*f2], a1 = b[2*f2+1];
  const float2* wp = (const float2*)w + f2;
  for(int o=0;o<256;++o){
    float2 u = wp[(size_t)o*50176];
    a0 += sz[o]*u.x; a1 += sz[o]*u.y;
  }
  out[2*f2]   = fmaxf(a0, 0.f);
  out[2*f2+1] = fmaxf(a1, 0.f);
}

// ---------- transposed conv 3x3 stride2 pad1 outpad1; ACT: 0=relu, 1=sigmoid ----------
template<int ACT>
__global__ __launch_bounds__(256) void k_deconv(const float* __restrict__ in, const float* __restrict__ w,
    const float* __restrict__ bias, float* __restrict__ out,
    int Cin, int Hin, int Win, int Cout){
  int Hout = Hin*2, Wout = Win*2;
  int idx = blockIdx.x*256 + threadIdx.x;
  int total = Cout*Hout*Wout;
  if(idx >= total) return;
  int ox = idx % Wout; int t = idx / Wout; int oy = t % Hout; int oc = t / Hout;
  float acc = bias[oc];
  for(int ic=0; ic<Cin; ++ic){
    const float* ip = in + ic*Hin*Win;
    const float* wp = w + (ic*Cout + oc)*9;
    #pragma unroll
    for(int ky=0; ky<3; ++ky){
      int ty = oy + 1 - ky;
      if(ty < 0 || (ty & 1)) continue;
      int iy = ty >> 1;
      if(iy >= Hin) continue;
      const float* row = ip + iy*Win;
      #pragma unroll
      for(int kx=0; kx<3; ++kx){
        int tx = ox + 1 - kx;
        if(tx < 0 || (tx & 1)) continue;
        int ix = tx >> 1;
        if(ix < Win) acc += row[ix] * wp[ky*3+kx];
      }
    }
  }
  if(ACT == 0) out[idx] = fmaxf(acc, 0.f);
  else         out[idx] = 1.f/(1.f + __expf(-acc));
}

extern "C" void kernel_launch(void* const* d_in, const int* in_sizes, int n_in,
                              void* d_out, int out_size, void* d_ws, size_t ws_size,
                              hipStream_t stream){
  const float* X    = (const float*)d_in[0];
  const float* EPS  = (const float*)d_in[1];
  const float* c1w  = (const float*)d_in[2];  const float* c1b = (const float*)d_in[3];
  const float* q1w  = (const float*)d_in[4];  const float* q1b = (const float*)d_in[5];
  const float* k1w  = (const float*)d_in[6];  const float* k1b = (const float*)d_in[7];
  const float* v1w  = (const float*)d_in[8];  const float* v1b = (const float*)d_in[9];
  const float* g1   = (const float*)d_in[10];
  const float* c2w  = (const float*)d_in[11]; const float* c2b = (const float*)d_in[12];
  const float* q2w  = (const float*)d_in[13]; const float* q2b = (const float*)d_in[14];
  const float* k2w  = (const float*)d_in[15]; const float* k2b = (const float*)d_in[16];
  const float* v2w  = (const float*)d_in[17]; const float* v2b = (const float*)d_in[18];
  const float* g2   = (const float*)d_in[19];
  const float* c3w  = (const float*)d_in[20]; const float* c3b = (const float*)d_in[21];
  const float* fmw  = (const float*)d_in[22]; const float* fmb = (const float*)d_in[23];
  const float* flw  = (const float*)d_in[24]; const float* flb = (const float*)d_in[25];
  const float* fdw  = (const float*)d_in[26]; const float* fdb = (const float*)d_in[27];
  const float* d1w  = (const float*)d_in[28]; const float* d1b = (const float*)d_in[29];
  const float* d2w  = (const float*)d_in[30]; const float* d2b = (const float*)d_in[31];
  const float* d3w  = (const float*)d_in[32]; const float* d3b = (const float*)d_in[33];

  float* ws  = (float*)d_ws;
  float* h1  = ws;            // 401408   [32][112][112]
  float* h1a = h1  + 401408;  // 401408
  float* q1  = h1a + 401408;  // 50176    [12544][4]
  float* k1  = q1  + 50176;   // 50176    [4][12544]
  float* v1  = k1  + 50176;   // 401408   [32][12544]
  float* h2  = v1  + 401408;  // 200704   [64][56][56]
  float* h2a = h2  + 200704;  // 200704
  float* q2  = h2a + 200704;  // 25088
  float* k2  = q2  + 25088;   // 25088
  float* v2  = k2  + 25088;   // 200704
  float* h3  = v2  + 200704;  // 100352   [128][28][28]
  float* pmu = h3  + 100352;  // 100352   (392 x 256)
  float* plv = pmu + 100352;  // 100352
  float* z   = plv + 100352;  // 256
  // decoder buffers alias dead encoder regions:
  float* dd0 = h1;            // 100352 (h1 dead after attn1)
  float* dd1 = h1 + 100352;   // 200704
  float* dd2 = h1a;           // 401408 (h1a dead after conv2)

  float* OUT = (float*)d_out;   // [recon 150528 | mu 256 | logvar 256], all f32

  k_conv_s2<<<dim3(1568),dim3(256),0,stream>>>(X, c1w, c1b, h1, 3,224,224, 32,112,112);
  k_qkv<32,4><<<dim3(49),dim3(256),0,stream>>>(h1, q1w,q1b, k1w,k1b, v1w,v1b, q1,k1,v1, 12544);
  k_attn<32,4,8,128><<<dim3(392),dim3(256),0,stream>>>(q1,k1,v1, h1, g1, h1a, 12544);
  k_conv_s2<<<dim3(784),dim3(256),0,stream>>>(h1a, c2w, c2b, h2, 32,112,112, 64,56,56);
  k_qkv<64,8><<<dim3(13),dim3(256),0,stream>>>(h2, q2w,q2b, k2w,k2b, v2w,v2b, q2,k2,v2, 3136);
  k_attn<64,8,16,64><<<dim3(196),dim3(256),0,stream>>>(q2,k2,v2, h2, g2, h2a, 3136);
  k_conv_s2<<<dim3(392),dim3(256),0,stream>>>(h2a, c3w, c3b, h3, 64,56,56, 128,28,28);
  k_fc2_part<<<dim3(392),dim3(128),0,stream>>>(h3, fmw, flw, pmu, plv);
  k_reparam<<<dim3(1),dim3(256),0,stream>>>(pmu, plv, fmb, flb, EPS, z, OUT+150528, OUT+150784);
  k_fc_dec<<<dim3(196),dim3(256),0,stream>>>(z, fdw, fdb, dd0);
  k_deconv<0><<<dim3(784),dim3(256),0,stream>>>(dd0, d1w, d1b, dd1, 128,28,28, 64);
  k_deconv<0><<<dim3(1568),dim3(256),0,stream>>>(dd1, d2w, d2b, dd2, 64,56,56, 32);
  k_deconv<1><<<dim3(588),dim3(256),0,stream>>>(dd2, d3w, d3b, OUT, 32,112,112, 3);
}

// Round 4
// 1064.521 us; speedup vs baseline: 1.1145x; 1.1145x over previous
//
#include <hip/hip_runtime.h>
#include <hip/hip_bf16.h>

// ---------- conv 3x3 stride2 pad1 + relu ----------
__global__ __launch_bounds__(256) void k_conv_s2(const float* __restrict__ in, const float* __restrict__ w,
    const float* __restrict__ bias, float* __restrict__ out,
    int Cin, int Hin, int Win, int Cout, int Hout, int Wout){
  int idx = blockIdx.x*256 + threadIdx.x;
  int total = Cout*Hout*Wout;
  if(idx >= total) return;
  int ox = idx % Wout; int t = idx / Wout; int oy = t % Hout; int oc = t / Hout;
  float acc = bias[oc];
  int iy0 = oy*2 - 1, ix0 = ox*2 - 1;
  for(int ic=0; ic<Cin; ++ic){
    const float* ip = in + ic*Hin*Win;
    const float* wp = w + (oc*Cin + ic)*9;
    #pragma unroll
    for(int ky=0; ky<3; ++ky){
      int iy = iy0 + ky;
      if((unsigned)iy >= (unsigned)Hin) continue;
      const float* row = ip + iy*Win;
      #pragma unroll
      for(int kx=0; kx<3; ++kx){
        int ix = ix0 + kx;
        if((unsigned)ix < (unsigned)Win) acc += row[ix] * wp[ky*3+kx];
      }
    }
  }
  out[idx] = fmaxf(acc, 0.f);
}

// ---------- q/k/v projections ----------
template<int C, int O>
__global__ __launch_bounds__(256) void k_qkv(const float* __restrict__ x,  // [C][N]
    const float* __restrict__ wq, const float* __restrict__ bq,
    const float* __restrict__ wk, const float* __restrict__ bk,
    const float* __restrict__ wv, const float* __restrict__ bv,
    float* __restrict__ q,  // [N][O]
    float* __restrict__ k,  // [O][N]
    float* __restrict__ v,  // [C][N]
    int N){
  int n = blockIdx.x*256 + threadIdx.x;
  if(n >= N) return;
  float xc[C];
  #pragma unroll
  for(int c=0;c<C;++c) xc[c] = x[c*N+n];
  #pragma unroll
  for(int o=0;o<O;++o){
    float aq = bq[o], ak = bk[o];
    #pragma unroll
    for(int c=0;c<C;++c){ aq += wq[o*C+c]*xc[c]; ak += wk[o*C+c]*xc[c]; }
    q[n*O+o] = aq;
    k[o*N+n] = ak;
  }
  for(int o=0;o<C;++o){
    float av = bv[o];
    #pragma unroll
    for(int c=0;c<C;++c) av += wv[o*C+c]*xc[c];
    v[o*N+n] = av;
  }
}

// ---------- flash-style attention + residual, 2 queries/thread ----------
// TPQ lanes split the key range; each thread owns queries m0 and m0+256/TPQ.
// K tile stored float4-swizzled (slot = s ^ (s>>3)) -> 2-way (free) bank access.
// V tile [c][j/4] float4. Butterfly shfl_xor combine over TPQ lanes.
template<int C, int O, int TPQ, int TN>
__global__ __launch_bounds__(256,1) void k_attn2q(const float* __restrict__ q, const float* __restrict__ kk,
    const float* __restrict__ v, const float* __restrict__ xin,
    const float* __restrict__ gamma, float* __restrict__ out, int N){
  constexpr int QW  = 256/TPQ;       // query groups per block
  constexpr int QPB = 2*QW;          // queries per block
  constexpr int KF4 = TN*O/4;
  constexpr int VF4 = C*TN/4;
  __shared__ float4 skb[KF4];
  __shared__ float4 svb[VF4];
  const int tid = threadIdx.x;
  const int qi = tid / TPQ, si = tid % TPQ;
  const int m0 = blockIdx.x*QPB + qi;
  const int m1 = m0 + QW;
  float qv0[O], qv1[O];
  #pragma unroll
  for(int o=0;o<O;++o){ qv0[o] = q[m0*O+o]; qv1[o] = q[m1*O+o]; }
  float acc0[C], acc1[C];
  #pragma unroll
  for(int c=0;c<C;++c){ acc0[c]=0.f; acc1[c]=0.f; }
  float den0=0.f, den1=0.f;
  const float4* v4 = (const float4*)v;
  for(int n0=0; n0<N; n0+=TN){
    __syncthreads();
    for(int s=tid; s<KF4; s+=256){
      int j = s/(O/4), h = s%(O/4);
      float4 kv;
      kv.x = kk[(h*4+0)*N + n0 + j];
      kv.y = kk[(h*4+1)*N + n0 + j];
      kv.z = kk[(h*4+2)*N + n0 + j];
      kv.w = kk[(h*4+3)*N + n0 + j];
      skb[s ^ (s>>3)] = kv;
    }
    for(int i=tid; i<VF4; i+=256){
      svb[i] = v4[(i/(TN/4))*(N/4) + n0/4 + (i%(TN/4))];
    }
    __syncthreads();
    #pragma unroll
    for(int it=0; it<TN/4/TPQ; ++it){
      const int jq = si + it*TPQ;
      float p0[4], p1[4];
      #pragma unroll
      for(int u=0;u<4;++u){
        int j = jq*4+u;
        float s0=0.f, s1=0.f;
        #pragma unroll
        for(int h=0; h<O/4; ++h){
          int s = j*(O/4)+h;
          float4 k4 = skb[s ^ (s>>3)];
          s0 += qv0[h*4+0]*k4.x + qv0[h*4+1]*k4.y + qv0[h*4+2]*k4.z + qv0[h*4+3]*k4.w;
          s1 += qv1[h*4+0]*k4.x + qv1[h*4+1]*k4.y + qv1[h*4+2]*k4.z + qv1[h*4+3]*k4.w;
        }
        p0[u] = __expf(s0);
        p1[u] = __expf(s1);
      }
      den0 += p0[0]+p0[1]+p0[2]+p0[3];
      den1 += p1[0]+p1[1]+p1[2]+p1[3];
      #pragma unroll
      for(int c=0;c<C;++c){
        float4 vv = svb[c*(TN/4)+jq];
        acc0[c] += p0[0]*vv.x + p0[1]*vv.y + p0[2]*vv.z + p0[3]*vv.w;
        acc1[c] += p1[0]*vv.x + p1[1]*vv.y + p1[2]*vv.z + p1[3]*vv.w;
      }
    }
  }
  #pragma unroll
  for(int off=1; off<TPQ; off<<=1){
    den0 += __shfl_xor(den0, off);
    den1 += __shfl_xor(den1, off);
    #pragma unroll
    for(int c=0;c<C;++c){ acc0[c] += __shfl_xor(acc0[c], off); acc1[c] += __shfl_xor(acc1[c], off); }
  }
  const float gm = gamma[0];
  const float g0 = gm/den0, g1 = gm/den1;
  #pragma unroll
  for(int c=0;c<C;++c){
    if((c % TPQ) == si){           // static acc index; 4 lanes/wave active per store
      out[c*N+m0] = acc0[c]*g0 + xin[c*N+m0];
      out[c*N+m1] = acc1[c]*g1 + xin[c*N+m1];
    }
  }
}

// ---------- fc_mu / fc_lv partial sums (chunk of 256 features per block) ----------
__global__ __launch_bounds__(128) void k_fc2_part(const float* __restrict__ hf,
    const float* __restrict__ wmu, const float* __restrict__ wlv,
    float* __restrict__ pmu, float* __restrict__ plv){
  __shared__ float sh[256];
  const int t = threadIdx.x;
  const int f0 = blockIdx.x * 256;
  for(int i=t; i<256; i+=128) sh[i] = hf[f0+i];
  __syncthreads();
  float a0=0.f, a1=0.f, c0=0.f, c1=0.f;
  const float2* wm = (const float2*)wmu + (size_t)f0*128 + t;   // 128 float2 per row of 256
  const float2* wl = (const float2*)wlv + (size_t)f0*128 + t;
  for(int j=0;j<256;++j){
    float h = sh[j];
    float2 um = wm[(size_t)j*128];
    float2 ul = wl[(size_t)j*128];
    a0 += h*um.x; a1 += h*um.y;
    c0 += h*ul.x; c1 += h*ul.y;
  }
  pmu[blockIdx.x*256 + 2*t]   = a0;
  pmu[blockIdx.x*256 + 2*t+1] = a1;
  plv[blockIdx.x*256 + 2*t]   = c0;
  plv[blockIdx.x*256 + 2*t+1] = c1;
}

// ---------- reduce partials + bias + reparametrize; emit mu/logvar (f32) ----------
__global__ __launch_bounds__(256) void k_reparam(const float* __restrict__ pmu, const float* __restrict__ plv,
    const float* __restrict__ bmu, const float* __restrict__ blv, const float* __restrict__ eps,
    float* __restrict__ z, float* __restrict__ omu, float* __restrict__ olv){
  const int o = threadIdx.x;
  float mu = bmu[o], lv = blv[o];
  for(int i=0;i<392;++i){ mu += pmu[i*256+o]; lv += plv[i*256+o]; }
  float zz = mu + eps[o] * expf(0.5f*lv);
  z[o] = zz;
  omu[o] = mu;
  olv[o] = lv;
}

// ---------- decoder fc: d = relu(z @ W + b), W [256][100352] ----------
__global__ __launch_bounds__(256) void k_fc_dec(const float* __restrict__ z, const float* __restrict__ w,
    const float* __restrict__ b, float* __restrict__ out){
  __shared__ float sz[256];
  const int t = threadIdx.x;
  sz[t] = z[t];
  __syncthreads();
  const int f2 = blockIdx.x*256 + t;   // pair index; FLAT/2 = 50176
  float a0 = b[2*f2], a1 = b[2*f2+1];
  const float2* wp = (const float2*)w + f2;
  for(int o=0;o<256;++o){
    float2 u = wp[(size_t)o*50176];
    a0 += sz[o]*u.x; a1 += sz[o]*u.y;
  }
  out[2*f2]   = fmaxf(a0, 0.f);
  out[2*f2+1] = fmaxf(a1, 0.f);
}

// ---------- transposed conv 3x3 stride2 pad1 outpad1; ACT: 0=relu, 1=sigmoid ----------
template<int ACT>
__global__ __launch_bounds__(256) void k_deconv(const float* __restrict__ in, const float* __restrict__ w,
    const float* __restrict__ bias, float* __restrict__ out,
    int Cin, int Hin, int Win, int Cout){
  int Hout = Hin*2, Wout = Win*2;
  int idx = blockIdx.x*256 + threadIdx.x;
  int total = Cout*Hout*Wout;
  if(idx >= total) return;
  int ox = idx % Wout; int t = idx / Wout; int oy = t % Hout; int oc = t / Hout;
  float acc = bias[oc];
  for(int ic=0; ic<Cin; ++ic){
    const float* ip = in + ic*Hin*Win;
    const float* wp = w + (ic*Cout + oc)*9;
    #pragma unroll
    for(int ky=0; ky<3; ++ky){
      int ty = oy + 1 - ky;
      if(ty < 0 || (ty & 1)) continue;
      int iy = ty >> 1;
      if(iy >= Hin) continue;
      const float* row = ip + iy*Win;
      #pragma unroll
      for(int kx=0; kx<3; ++kx){
        int tx = ox + 1 - kx;
        if(tx < 0 || (tx & 1)) continue;
        int ix = tx >> 1;
        if(ix < Win) acc += row[ix] * wp[ky*3+kx];
      }
    }
  }
  if(ACT == 0) out[idx] = fmaxf(acc, 0.f);
  else         out[idx] = 1.f/(1.f + __expf(-acc));
}

extern "C" void kernel_launch(void* const* d_in, const int* in_sizes, int n_in,
                              void* d_out, int out_size, void* d_ws, size_t ws_size,
                              hipStream_t stream){
  const float* X    = (const float*)d_in[0];
  const float* EPS  = (const float*)d_in[1];
  const float* c1w  = (const float*)d_in[2];  const float* c1b = (const float*)d_in[3];
  const float* q1w  = (const float*)d_in[4];  const float* q1b = (const float*)d_in[5];
  const float* k1w  = (const float*)d_in[6];  const float* k1b = (const float*)d_in[7];
  const float* v1w  = (const float*)d_in[8];  const float* v1b = (const float*)d_in[9];
  const float* g1   = (const float*)d_in[10];
  const float* c2w  = (const float*)d_in[11]; const float* c2b = (const float*)d_in[12];
  const float* q2w  = (const float*)d_in[13]; const float* q2b = (const float*)d_in[14];
  const float* k2w  = (const float*)d_in[15]; const float* k2b = (const float*)d_in[16];
  const float* v2w  = (const float*)d_in[17]; const float* v2b = (const float*)d_in[18];
  const float* g2   = (const float*)d_in[19];
  const float* c3w  = (const float*)d_in[20]; const float* c3b = (const float*)d_in[21];
  const float* fmw  = (const float*)d_in[22]; const float* fmb = (const float*)d_in[23];
  const float* flw  = (const float*)d_in[24]; const float* flb = (const float*)d_in[25];
  const float* fdw  = (const float*)d_in[26]; const float* fdb = (const float*)d_in[27];
  const float* d1w  = (const float*)d_in[28]; const float* d1b = (const float*)d_in[29];
  const float* d2w  = (const float*)d_in[30]; const float* d2b = (const float*)d_in[31];
  const float* d3w  = (const float*)d_in[32]; const float* d3b = (const float*)d_in[33];

  float* ws  = (float*)d_ws;
  float* h1  = ws;            // 401408   [32][112][112]
  float* h1a = h1  + 401408;  // 401408
  float* q1  = h1a + 401408;  // 50176    [12544][4]
  float* k1  = q1  + 50176;   // 50176    [4][12544]
  float* v1  = k1  + 50176;   // 401408   [32][12544]
  float* h2  = v1  + 401408;  // 200704   [64][56][56]
  float* h2a = h2  + 200704;  // 200704
  float* q2  = h2a + 200704;  // 25088
  float* k2  = q2  + 25088;   // 25088
  float* v2  = k2  + 25088;   // 200704
  float* h3  = v2  + 200704;  // 100352   [128][28][28]
  float* pmu = h3  + 100352;  // 100352   (392 x 256)
  float* plv = pmu + 100352;  // 100352
  float* z   = plv + 100352;  // 256
  // decoder buffers alias dead encoder regions:
  float* dd0 = h1;            // 100352 (h1 dead after attn1)
  float* dd1 = h1 + 100352;   // 200704
  float* dd2 = h1a;           // 401408 (h1a dead after conv2)

  float* OUT = (float*)d_out;   // [recon 150528 | mu 256 | logvar 256], all f32

  k_conv_s2<<<dim3(1568),dim3(256),0,stream>>>(X, c1w, c1b, h1, 3,224,224, 32,112,112);
  k_qkv<32,4><<<dim3(49),dim3(256),0,stream>>>(h1, q1w,q1b, k1w,k1b, v1w,v1b, q1,k1,v1, 12544);
  k_attn2q<32,4,16,128><<<dim3(392),dim3(256),0,stream>>>(q1,k1,v1, h1, g1, h1a, 12544);
  k_conv_s2<<<dim3(784),dim3(256),0,stream>>>(h1a, c2w, c2b, h2, 32,112,112, 64,56,56);
  k_qkv<64,8><<<dim3(13),dim3(256),0,stream>>>(h2, q2w,q2b, k2w,k2b, v2w,v2b, q2,k2,v2, 3136);
  k_attn2q<64,8,16,64><<<dim3(98),dim3(256),0,stream>>>(q2,k2,v2, h2, g2, h2a, 3136);
  k_conv_s2<<<dim3(392),dim3(256),0,stream>>>(h2a, c3w, c3b, h3, 64,56,56, 128,28,28);
  k_fc2_part<<<dim3(392),dim3(128),0,stream>>>(h3, fmw, flw, pmu, plv);
  k_reparam<<<dim3(1),dim3(256),0,stream>>>(pmu, plv, fmb, flb, EPS, z, OUT+150528, OUT+150784);
  k_fc_dec<<<dim3(196),dim3(256),0,stream>>>(z, fdw, fdb, dd0);
  k_deconv<0><<<dim3(784),dim3(256),0,stream>>>(dd0, d1w, d1b, dd1, 128,28,28, 64);
  k_deconv<0><<<dim3(1568),dim3(256),0,stream>>>(dd1, d2w, d2b, dd2, 64,56,56, 32);
  k_deconv<1><<<dim3(588),dim3(256),0,stream>>>(dd2, d3w, d3b, OUT, 32,112,112, 3);
}

// Round 5
// 723.113 us; speedup vs baseline: 1.6408x; 1.4721x over previous
//
#include <hip/hip_runtime.h>
#include <hip/hip_bf16.h>

typedef __attribute__((ext_vector_type(8))) short short8v;   // 8 x bf16 (4 VGPR) MFMA frag
typedef __attribute__((ext_vector_type(4))) float f32x4;

__device__ __forceinline__ unsigned int f2b(float f){        // f32 -> bf16 bits, RNE
  unsigned int u = __float_as_uint(f);
  return (u + 0x7fffu + ((u>>16)&1u)) >> 16;
}
__device__ __forceinline__ unsigned int pkbf(float lo, float hi){ return f2b(lo) | (f2b(hi)<<16); }

// ---------- conv 3x3 stride2 pad1 + relu ----------
__global__ __launch_bounds__(256) void k_conv_s2(const float* __restrict__ in, const float* __restrict__ w,
    const float* __restrict__ bias, float* __restrict__ out,
    int Cin, int Hin, int Win, int Cout, int Hout, int Wout){
  int idx = blockIdx.x*256 + threadIdx.x;
  int total = Cout*Hout*Wout;
  if(idx >= total) return;
  int ox = idx % Wout; int t = idx / Wout; int oy = t % Hout; int oc = t / Hout;
  float acc = bias[oc];
  int iy0 = oy*2 - 1, ix0 = ox*2 - 1;
  for(int ic=0; ic<Cin; ++ic){
    const float* ip = in + ic*Hin*Win;
    const float* wp = w + (oc*Cin + ic)*9;
    #pragma unroll
    for(int ky=0; ky<3; ++ky){
      int iy = iy0 + ky;
      if((unsigned)iy >= (unsigned)Hin) continue;
      const float* row = ip + iy*Win;
      #pragma unroll
      for(int kx=0; kx<3; ++kx){
        int ix = ix0 + kx;
        if((unsigned)ix < (unsigned)Win) acc += row[ix] * wp[ky*3+kx];
      }
    }
  }
  out[idx] = fmaxf(acc, 0.f);
}

// ---------- q/k/v projections ----------
template<int C, int O>
__global__ __launch_bounds__(256) void k_qkv(const float* __restrict__ x,  // [C][N]
    const float* __restrict__ wq, const float* __restrict__ bq,
    const float* __restrict__ wk, const float* __restrict__ bk,
    const float* __restrict__ wv, const float* __restrict__ bv,
    float* __restrict__ q,  // [N][O]
    float* __restrict__ k,  // [O][N]
    float* __restrict__ v,  // [C][N]
    int N){
  int n = blockIdx.x*256 + threadIdx.x;
  if(n >= N) return;
  float xc[C];
  #pragma unroll
  for(int c=0;c<C;++c) xc[c] = x[c*N+n];
  #pragma unroll
  for(int o=0;o<O;++o){
    float aq = bq[o], ak = bk[o];
    #pragma unroll
    for(int c=0;c<C;++c){ aq += wq[o*C+c]*xc[c]; ak += wk[o*C+c]*xc[c]; }
    q[n*O+o] = aq;
    k[o*N+n] = ak;
  }
  for(int o=0;o<C;++o){
    float av = bv[o];
    #pragma unroll
    for(int c=0;c<C;++c) av += wv[o*C+c]*xc[c];
    v[o*N+n] = av;
  }
}

// ---------- MFMA flash attention, partial (key-split) ----------
// Block = 4 waves x 16 queries = 64 queries; keys [split*N/NSPLIT, ...+N/NSPLIT).
// Lane l computes scores for query (l&15), keys (l>>4)*8..+7 of each 32-slice (VALU, O fma each),
// exps, packs bf16 -> exactly the mfma_f32_16x16x32_bf16 A-frag. V staged bf16 in LDS rows
// [c][ST keys] (stride ST*2+16 B); B-frag = one ds_read_b128. Partial acc/den written to ws.
template<int C, int O, int ST, int NSPLIT>
__global__ __launch_bounds__(256) void k_attn_mfma(
    const float* __restrict__ q, const float* __restrict__ kk, const float* __restrict__ v,
    float* __restrict__ pacc, float* __restrict__ pden, int N){
  constexpr int NT = C/16;
  constexpr int VROW = ST*2 + 16;        // bytes; word-stride % 8 == 4 for ST mult of 16
  __shared__ __align__(16) char vsm[C*VROW];
  __shared__ float ksm[ST][O];           // xor-swizzled rows
  const int tid = threadIdx.x;
  const int qblk = blockIdx.x / NSPLIT, split = blockIdx.x % NSPLIT;
  const int KEYS = N / NSPLIT;
  const int kbase = split * KEYS;
  const int wv = tid >> 6;
  const int l  = tid & 63;
  const int lg = l >> 4, lq = l & 15;
  const int mq = qblk*64 + wv*16 + lq;   // query whose scores this lane computes
  float qv[O];
  #pragma unroll
  for(int o=0;o<O;++o) qv[o] = q[mq*O+o];
  f32x4 acc[NT];
  #pragma unroll
  for(int nt=0;nt<NT;++nt) acc[nt] = (f32x4){0.f,0.f,0.f,0.f};
  float den = 0.f;

  for(int g0=0; g0<KEYS; g0+=ST){
    __syncthreads();
    for(int j=tid; j<ST; j+=256){
      int jj = j ^ ((j>>3)&7);
      #pragma unroll
      for(int o=0;o<O;++o) ksm[jj][o] = kk[o*N + kbase + g0 + j];
    }
    for(int ch=tid; ch < C*(ST/8); ch += 256){
      int c = ch / (ST/8), j8 = ch % (ST/8);
      const float4* vp4 = (const float4*)(v + (size_t)c*N + kbase + g0 + j8*8);
      float4 a = vp4[0], b = vp4[1];
      uint4 wr; wr.x = pkbf(a.x,a.y); wr.y = pkbf(a.z,a.w); wr.z = pkbf(b.x,b.y); wr.w = pkbf(b.z,b.w);
      *(uint4*)(vsm + c*VROW + j8*16) = wr;
    }
    __syncthreads();
    #pragma unroll
    for(int s=0; s<ST/32; ++s){
      union { unsigned int u[4]; short8v s8; } pa;
      float dl = 0.f;
      #pragma unroll
      for(int u=0; u<4; ++u){
        float pr[2];
        #pragma unroll
        for(int hh=0; hh<2; ++hh){
          int key = s*32 + lg*8 + u*2 + hh;
          int kr = key ^ ((key>>3)&7);
          float sc = 0.f;
          #pragma unroll
          for(int o=0;o<O;++o) sc += qv[o]*ksm[kr][o];
          pr[hh] = __expf(sc);
          dl += pr[hh];
        }
        pa.u[u] = pkbf(pr[0], pr[1]);
      }
      den += dl;
      #pragma unroll
      for(int nt=0; nt<NT; ++nt){
        short8v bf_ = *(const short8v*)(vsm + (lq + nt*16)*VROW + (s*32 + lg*8)*2);
        acc[nt] = __builtin_amdgcn_mfma_f32_16x16x32_bf16(pa.s8, bf_, acc[nt], 0,0,0);
      }
    }
  }
  den += __shfl_xor(den, 16);
  den += __shfl_xor(den, 32);
  if(lg == 0) pden[(size_t)split*N + qblk*64 + wv*16 + lq] = den;
  #pragma unroll
  for(int nt=0; nt<NT; ++nt){
    #pragma unroll
    for(int r=0;r<4;++r){
      int qg = qblk*64 + wv*16 + lg*4 + r;       // C/D: row=(l>>4)*4+r, col=l&15
      pacc[((size_t)split*N + qg)*C + nt*16 + lq] = acc[nt][r];
    }
  }
}

// ---------- attention combine: out = gamma * (sum acc)/(sum den) + xin ----------
template<int C, int NSPLIT>
__global__ __launch_bounds__(256) void k_attn_comb(const float* __restrict__ pacc, const float* __restrict__ pden,
    const float* __restrict__ xin, const float* __restrict__ gamma, float* __restrict__ out, int N){
  int idx = blockIdx.x*256 + threadIdx.x;
  if(idx >= N*C) return;
  int c = idx / N, m = idx - c*N;
  float a = 0.f, d = 0.f;
  #pragma unroll
  for(int s=0;s<NSPLIT;++s){
    a += pacc[((size_t)s*N + m)*C + c];
    d += pden[(size_t)s*N + m];
  }
  out[idx] = gamma[0]*a/d + xin[idx];
}

// ---------- fc_mu / fc_lv partial sums (chunk of 256 features per block) ----------
__global__ __launch_bounds__(128) void k_fc2_part(const float* __restrict__ hf,
    const float* __restrict__ wmu, const float* __restrict__ wlv,
    float* __restrict__ pmu, float* __restrict__ plv){
  __shared__ float sh[256];
  const int t = threadIdx.x;
  const int f0 = blockIdx.x * 256;
  for(int i=t; i<256; i+=128) sh[i] = hf[f0+i];
  __syncthreads();
  float a0=0.f, a1=0.f, c0=0.f, c1=0.f;
  const float2* wm = (const float2*)wmu + (size_t)f0*128 + t;
  const float2* wl = (const float2*)wlv + (size_t)f0*128 + t;
  for(int j=0;j<256;++j){
    float h = sh[j];
    float2 um = wm[(size_t)j*128];
    float2 ul = wl[(size_t)j*128];
    a0 += h*um.x; a1 += h*um.y;
    c0 += h*ul.x; c1 += h*ul.y;
  }
  pmu[blockIdx.x*256 + 2*t]   = a0;
  pmu[blockIdx.x*256 + 2*t+1] = a1;
  plv[blockIdx.x*256 + 2*t]   = c0;
  plv[blockIdx.x*256 + 2*t+1] = c1;
}

// ---------- reduce partials + bias + reparametrize; emit mu/logvar (f32) ----------
__global__ __launch_bounds__(256) void k_reparam(const float* __restrict__ pmu, const float* __restrict__ plv,
    const float* __restrict__ bmu, const float* __restrict__ blv, const float* __restrict__ eps,
    float* __restrict__ z, float* __restrict__ omu, float* __restrict__ olv){
  const int o = threadIdx.x;
  float mu = bmu[o], lv = blv[o];
  for(int i=0;i<392;++i){ mu += pmu[i*256+o]; lv += plv[i*256+o]; }
  float zz = mu + eps[o] * expf(0.5f*lv);
  z[o] = zz;
  omu[o] = mu;
  olv[o] = lv;
}

// ---------- decoder fc: d = relu(z @ W + b), W [256][100352] ----------
__global__ __launch_bounds__(256) void k_fc_dec(const float* __restrict__ z, const float* __restrict__ w,
    const float* __restrict__ b, float* __restrict__ out){
  __shared__ float sz[256];
  const int t = threadIdx.x;
  sz[t] = z[t];
  __syncthreads();
  const int f2 = blockIdx.x*256 + t;
  float a0 = b[2*f2], a1 = b[2*f2+1];
  const float2* wp = (const float2*)w + f2;
  for(int o=0;o<256;++o){
    float2 u = wp[(size_t)o*50176];
    a0 += sz[o]*u.x; a1 += sz[o]*u.y;
  }
  out[2*f2]   = fmaxf(a0, 0.f);
  out[2*f2+1] = fmaxf(a1, 0.f);
}

// ---------- transposed conv 3x3 stride2 pad1 outpad1; ACT: 0=relu, 1=sigmoid ----------
template<int ACT>
__global__ __launch_bounds__(256) void k_deconv(const float* __restrict__ in, const float* __restrict__ w,
    const float* __restrict__ bias, float* __restrict__ out,
    int Cin, int Hin, int Win, int Cout){
  int Hout = Hin*2, Wout = Win*2;
  int idx = blockIdx.x*256 + threadIdx.x;
  int total = Cout*Hout*Wout;
  if(idx >= total) return;
  int ox = idx % Wout; int t = idx / Wout; int oy = t % Hout; int oc = t / Hout;
  float acc = bias[oc];
  for(int ic=0; ic<Cin; ++ic){
    const float* ip = in + ic*Hin*Win;
    const float* wp = w + (ic*Cout + oc)*9;
    #pragma unroll
    for(int ky=0; ky<3; ++ky){
      int ty = oy + 1 - ky;
      if(ty < 0 || (ty & 1)) continue;
      int iy = ty >> 1;
      if(iy >= Hin) continue;
      const float* row = ip + iy*Win;
      #pragma unroll
      for(int kx=0; kx<3; ++kx){
        int tx = ox + 1 - kx;
        if(tx < 0 || (tx & 1)) continue;
        int ix = tx >> 1;
        if(ix < Win) acc += row[ix] * wp[ky*3+kx];
      }
    }
  }
  if(ACT == 0) out[idx] = fmaxf(acc, 0.f);
  else         out[idx] = 1.f/(1.f + __expf(-acc));
}

extern "C" void kernel_launch(void* const* d_in, const int* in_sizes, int n_in,
                              void* d_out, int out_size, void* d_ws, size_t ws_size,
                              hipStream_t stream){
  const float* X    = (const float*)d_in[0];
  const float* EPS  = (const float*)d_in[1];
  const float* c1w  = (const float*)d_in[2];  const float* c1b = (const float*)d_in[3];
  const float* q1w  = (const float*)d_in[4];  const float* q1b = (const float*)d_in[5];
  const float* k1w  = (const float*)d_in[6];  const float* k1b = (const float*)d_in[7];
  const float* v1w  = (const float*)d_in[8];  const float* v1b = (const float*)d_in[9];
  const float* g1   = (const float*)d_in[10];
  const float* c2w  = (const float*)d_in[11]; const float* c2b = (const float*)d_in[12];
  const float* q2w  = (const float*)d_in[13]; const float* q2b = (const float*)d_in[14];
  const float* k2w  = (const float*)d_in[15]; const float* k2b = (const float*)d_in[16];
  const float* v2w  = (const float*)d_in[17]; const float* v2b = (const float*)d_in[18];
  const float* g2   = (const float*)d_in[19];
  const float* c3w  = (const float*)d_in[20]; const float* c3b = (const float*)d_in[21];
  const float* fmw  = (const float*)d_in[22]; const float* fmb = (const float*)d_in[23];
  const float* flw  = (const float*)d_in[24]; const float* flb = (const float*)d_in[25];
  const float* fdw  = (const float*)d_in[26]; const float* fdb = (const float*)d_in[27];
  const float* d1w  = (const float*)d_in[28]; const float* d1b = (const float*)d_in[29];
  const float* d2w  = (const float*)d_in[30]; const float* d2b = (const float*)d_in[31];
  const float* d3w  = (const float*)d_in[32]; const float* d3b = (const float*)d_in[33];

  float* ws  = (float*)d_ws;
  float* h1  = ws;            // 401408   [32][112][112]
  float* h1a = h1  + 401408;  // 401408
  float* q1  = h1a + 401408;  // 50176    [12544][4]
  float* k1  = q1  + 50176;   // 50176    [4][12544]
  float* v1  = k1  + 50176;   // 401408   [32][12544]
  float* h2  = v1  + 401408;  // 200704   [64][56][56]
  float* h2a = h2  + 200704;  // 200704
  float* q2  = h2a + 200704;  // 25088
  float* k2  = q2  + 25088;   // 25088
  float* v2  = k2  + 25088;   // 200704
  float* h3  = v2  + 200704;  // 100352   [128][28][28]
  float* pmu = h3  + 100352;  // 100352   (392 x 256)
  float* plv = pmu + 100352;  // 100352
  float* z   = plv + 100352;  // 256
  float* part= z   + 256;     // attn partial acc (max 7*3136*64 = 1404928)
  float* pdn = part+ 1404928; // attn partial den (max 7*3136 = 21952)
  // decoder buffers alias dead encoder regions:
  float* dd0 = h1;            // 100352 (h1 dead after attn1 combine)
  float* dd1 = h1 + 100352;   // 200704
  float* dd2 = h1a;           // 401408 (h1a dead after conv2)

  float* OUT = (float*)d_out;   // [recon 150528 | mu 256 | logvar 256], all f32

  k_conv_s2<<<dim3(1568),dim3(256),0,stream>>>(X, c1w, c1b, h1, 3,224,224, 32,112,112);
  k_qkv<32,4><<<dim3(49),dim3(256),0,stream>>>(h1, q1w,q1b, k1w,k1b, v1w,v1b, q1,k1,v1, 12544);
  k_attn_mfma<32,4,128,2><<<dim3(392),dim3(256),0,stream>>>(q1,k1,v1, part, pdn, 12544);
  k_attn_comb<32,2><<<dim3(1568),dim3(256),0,stream>>>(part, pdn, h1, g1, h1a, 12544);
  k_conv_s2<<<dim3(784),dim3(256),0,stream>>>(h1a, c2w, c2b, h2, 32,112,112, 64,56,56);
  k_qkv<64,8><<<dim3(13),dim3(256),0,stream>>>(h2, q2w,q2b, k2w,k2b, v2w,v2b, q2,k2,v2, 3136);
  k_attn_mfma<64,8,64,7><<<dim3(343),dim3(256),0,stream>>>(q2,k2,v2, part, pdn, 3136);
  k_attn_comb<64,7><<<dim3(784),dim3(256),0,stream>>>(part, pdn, h2, g2, h2a, 3136);
  k_conv_s2<<<dim3(392),dim3(256),0,stream>>>(h2a, c3w, c3b, h3, 64,56,56, 128,28,28);
  k_fc2_part<<<dim3(392),dim3(128),0,stream>>>(h3, fmw, flw, pmu, plv);
  k_reparam<<<dim3(1),dim3(256),0,stream>>>(pmu, plv, fmb, flb, EPS, z, OUT+150528, OUT+150784);
  k_fc_dec<<<dim3(196),dim3(256),0,stream>>>(z, fdw, fdb, dd0);
  k_deconv<0><<<dim3(784),dim3(256),0,stream>>>(dd0, d1w, d1b, dd1, 128,28,28, 64);
  k_deconv<0><<<dim3(1568),dim3(256),0,stream>>>(dd1, d2w, d2b, dd2, 64,56,56, 32);
  k_deconv<1><<<dim3(588),dim3(256),0,stream>>>(dd2, d3w, d3b, OUT, 32,112,112, 3);
}

// Round 6
// 665.042 us; speedup vs baseline: 1.7840x; 1.0873x over previous
//
#include <hip/hip_runtime.h>
#include <hip/hip_bf16.h>

typedef __hip_bfloat16 bf16;
typedef __attribute__((ext_vector_type(8))) short short8v;   // 8 x bf16 (4 VGPR) MFMA frag
typedef __attribute__((ext_vector_type(4))) float f32x4;

__device__ __forceinline__ unsigned int f2b(float f){        // f32 -> bf16 bits, RNE
  unsigned int u = __float_as_uint(f);
  return (u + 0x7fffu + ((u>>16)&1u)) >> 16;
}
__device__ __forceinline__ unsigned int pkbf(float lo, float hi){ return f2b(lo) | (f2b(hi)<<16); }

// ---------- conv 3x3 stride2 pad1 + relu ----------
__global__ __launch_bounds__(256) void k_conv_s2(const float* __restrict__ in, const float* __restrict__ w,
    const float* __restrict__ bias, float* __restrict__ out,
    int Cin, int Hin, int Win, int Cout, int Hout, int Wout){
  int idx = blockIdx.x*256 + threadIdx.x;
  int total = Cout*Hout*Wout;
  if(idx >= total) return;
  int ox = idx % Wout; int t = idx / Wout; int oy = t % Hout; int oc = t / Hout;
  float acc = bias[oc];
  int iy0 = oy*2 - 1, ix0 = ox*2 - 1;
  for(int ic=0; ic<Cin; ++ic){
    const float* ip = in + ic*Hin*Win;
    const float* wp = w + (oc*Cin + ic)*9;
    #pragma unroll
    for(int ky=0; ky<3; ++ky){
      int iy = iy0 + ky;
      if((unsigned)iy >= (unsigned)Hin) continue;
      const float* row = ip + iy*Win;
      #pragma unroll
      for(int kx=0; kx<3; ++kx){
        int ix = ix0 + kx;
        if((unsigned)ix < (unsigned)Win) acc += row[ix] * wp[ky*3+kx];
      }
    }
  }
  out[idx] = fmaxf(acc, 0.f);
}

// ---------- q/k/v projections, TPN threads per token; v stored bf16 ----------
template<int C, int O, int TPN>
__global__ __launch_bounds__(256) void k_qkv(const float* __restrict__ x,  // [C][N]
    const float* __restrict__ wq, const float* __restrict__ bq,
    const float* __restrict__ wk, const float* __restrict__ bk,
    const float* __restrict__ wv, const float* __restrict__ bv,
    float* __restrict__ q,  // [N][O]
    float* __restrict__ k,  // [O][N]
    bf16* __restrict__ v,   // [C][N] bf16
    int N){
  constexpr int NPB = 256/TPN;
  constexpr int OP = O/TPN > 0 ? O/TPN : 1;
  constexpr int CP = C/TPN;
  const int n = blockIdx.x*NPB + threadIdx.x/TPN;
  const int p = threadIdx.x%TPN;
  float xc[C];
  #pragma unroll
  for(int c=0;c<C;++c) xc[c] = x[c*N+n];
  #pragma unroll
  for(int oo=0;oo<OP;++oo){
    int o = p*OP + oo;
    float aq = bq[o], ak = bk[o];
    #pragma unroll
    for(int c=0;c<C;++c){ aq += wq[o*C+c]*xc[c]; ak += wk[o*C+c]*xc[c]; }
    q[n*O+o] = aq;
    k[o*N+n] = ak;
  }
  #pragma unroll
  for(int cc=0;cc<CP;++cc){
    int o = p*CP + cc;
    float av = bv[o];
    #pragma unroll
    for(int c=0;c<C;++c) av += wv[o*C+c]*xc[c];
    v[o*N+n] = __float2bfloat16(av);
  }
}

// ---------- MFMA flash attention, partial (key-split) ----------
// Block = 4 waves x 16 queries = 64 queries; keys [split*KEYS, +KEYS).
// Lane l: scores for query (l&15), keys (l>>4)*8..+7 of each 32-slice via float4 K rows,
// exp, pack bf16 -> mfma A-frag. V bf16 rows in LDS, B-frag = ds_read_b128.
template<int C, int O, int ST, int NSPLIT>
__global__ __launch_bounds__(256) void k_attn_mfma(
    const float* __restrict__ q, const float* __restrict__ kk, const bf16* __restrict__ vb,
    float* __restrict__ pacc, float* __restrict__ pden, int N){
  constexpr int NT = C/16;
  constexpr int OF4 = O/4;
  constexpr int VROW = ST*2 + 16;        // bytes; word-stride % 32 == 4
  __shared__ __align__(16) char vsm[C*VROW];
  __shared__ float4 ksm4[ST*OF4];        // xor-swizzled rows of O floats
  const int tid = threadIdx.x;
  const int qblk = blockIdx.x / NSPLIT, split = blockIdx.x % NSPLIT;
  const int KEYS = N / NSPLIT;
  const int kbase = split * KEYS;
  const int wv = tid >> 6;
  const int l  = tid & 63;
  const int lg = l >> 4, lq = l & 15;
  const int mq = qblk*64 + wv*16 + lq;
  float qv[O];
  #pragma unroll
  for(int o=0;o<O;++o) qv[o] = q[mq*O+o];
  f32x4 acc[NT];
  #pragma unroll
  for(int nt=0;nt<NT;++nt) acc[nt] = (f32x4){0.f,0.f,0.f,0.f};
  float den = 0.f;

  for(int g0=0; g0<KEYS; g0+=ST){
    __syncthreads();
    for(int j=tid; j<ST; j+=256){
      int jj = j ^ ((j>>3)&7);
      #pragma unroll
      for(int h=0;h<OF4;++h){
        float4 kv;
        ((float*)&kv)[0] = kk[(h*4+0)*N + kbase + g0 + j];
        ((float*)&kv)[1] = kk[(h*4+1)*N + kbase + g0 + j];
        ((float*)&kv)[2] = kk[(h*4+2)*N + kbase + g0 + j];
        ((float*)&kv)[3] = kk[(h*4+3)*N + kbase + g0 + j];
        ksm4[jj*OF4 + h] = kv;
      }
    }
    for(int ch=tid; ch < C*(ST/8); ch += 256){
      int c = ch / (ST/8), j8 = ch % (ST/8);
      *(uint4*)(vsm + c*VROW + j8*16) =
          *(const uint4*)(vb + (size_t)c*N + kbase + g0 + j8*8);
    }
    __syncthreads();
    #pragma unroll
    for(int s=0; s<ST/32; ++s){
      union { unsigned int u[4]; short8v s8; } pa;
      float dl = 0.f;
      #pragma unroll
      for(int u=0; u<4; ++u){
        float pr[2];
        #pragma unroll
        for(int hh=0; hh<2; ++hh){
          int key = s*32 + lg*8 + u*2 + hh;
          int kr = key ^ ((key>>3)&7);
          float sc = 0.f;
          #pragma unroll
          for(int h=0;h<OF4;++h){
            float4 k4 = ksm4[kr*OF4 + h];
            sc += qv[h*4+0]*k4.x + qv[h*4+1]*k4.y + qv[h*4+2]*k4.z + qv[h*4+3]*k4.w;
          }
          pr[hh] = __expf(sc);
          dl += pr[hh];
        }
        pa.u[u] = pkbf(pr[0], pr[1]);
      }
      den += dl;
      #pragma unroll
      for(int nt=0; nt<NT; ++nt){
        short8v bf_ = *(const short8v*)(vsm + (lq + nt*16)*VROW + (s*32 + lg*8)*2);
        acc[nt] = __builtin_amdgcn_mfma_f32_16x16x32_bf16(pa.s8, bf_, acc[nt], 0,0,0);
      }
    }
  }
  den += __shfl_xor(den, 16);
  den += __shfl_xor(den, 32);
  if(lg == 0) pden[(size_t)split*N + qblk*64 + wv*16 + lq] = den;
  #pragma unroll
  for(int nt=0; nt<NT; ++nt){
    #pragma unroll
    for(int r=0;r<4;++r){
      int qg = qblk*64 + wv*16 + lg*4 + r;       // C/D: row=(l>>4)*4+r, col=l&15
      pacc[((size_t)split*N + qg)*C + nt*16 + lq] = acc[nt][r];
    }
  }
}

// ---------- attention combine: out = gamma * (sum acc)/(sum den) + xin ----------
template<int C, int NSPLIT>
__global__ __launch_bounds__(256) void k_attn_comb(const float* __restrict__ pacc, const float* __restrict__ pden,
    const float* __restrict__ xin, const float* __restrict__ gamma, float* __restrict__ out, int N){
  int idx = blockIdx.x*256 + threadIdx.x;
  if(idx >= N*C) return;
  int c = idx / N, m = idx - c*N;
  float a = 0.f, d = 0.f;
  #pragma unroll
  for(int s=0;s<NSPLIT;++s){
    a += pacc[((size_t)s*N + m)*C + c];
    d += pden[(size_t)s*N + m];
  }
  out[idx] = gamma[0]*a/d + xin[idx];
}

// ---------- fc_mu / fc_lv partial sums (chunk of 256 features per block) ----------
__global__ __launch_bounds__(128) void k_fc2_part(const float* __restrict__ hf,
    const float* __restrict__ wmu, const float* __restrict__ wlv,
    float* __restrict__ pmu, float* __restrict__ plv){
  __shared__ float sh[256];
  const int t = threadIdx.x;
  const int f0 = blockIdx.x * 256;
  for(int i=t; i<256; i+=128) sh[i] = hf[f0+i];
  __syncthreads();
  float a0=0.f, a1=0.f, c0=0.f, c1=0.f;
  const float2* wm = (const float2*)wmu + (size_t)f0*128 + t;
  const float2* wl = (const float2*)wlv + (size_t)f0*128 + t;
  for(int j=0;j<256;++j){
    float h = sh[j];
    float2 um = wm[(size_t)j*128];
    float2 ul = wl[(size_t)j*128];
    a0 += h*um.x; a1 += h*um.y;
    c0 += h*ul.x; c1 += h*ul.y;
  }
  pmu[blockIdx.x*256 + 2*t]   = a0;
  pmu[blockIdx.x*256 + 2*t+1] = a1;
  plv[blockIdx.x*256 + 2*t]   = c0;
  plv[blockIdx.x*256 + 2*t+1] = c1;
}

// ---------- reduce partials + bias + reparametrize; emit mu/logvar (f32) ----------
__global__ __launch_bounds__(256) void k_reparam(const float* __restrict__ pmu, const float* __restrict__ plv,
    const float* __restrict__ bmu, const float* __restrict__ blv, const float* __restrict__ eps,
    float* __restrict__ z, float* __restrict__ omu, float* __restrict__ olv){
  const int o = threadIdx.x;
  float mu = bmu[o], lv = blv[o];
  for(int i=0;i<392;++i){ mu += pmu[i*256+o]; lv += plv[i*256+o]; }
  float zz = mu + eps[o] * expf(0.5f*lv);
  z[o] = zz;
  omu[o] = mu;
  olv[o] = lv;
}

// ---------- decoder fc: d = relu(z @ W + b), W [256][100352] ----------
__global__ __launch_bounds__(256) void k_fc_dec(const float* __restrict__ z, const float* __restrict__ w,
    const float* __restrict__ b, float* __restrict__ out){
  __shared__ float sz[256];
  const int t = threadIdx.x;
  sz[t] = z[t];
  __syncthreads();
  const int f2 = blockIdx.x*256 + t;
  float a0 = b[2*f2], a1 = b[2*f2+1];
  const float2* wp = (const float2*)w + f2;
  for(int o=0;o<256;++o){
    float2 u = wp[(size_t)o*50176];
    a0 += sz[o]*u.x; a1 += sz[o]*u.y;
  }
  out[2*f2]   = fmaxf(a0, 0.f);
  out[2*f2+1] = fmaxf(a1, 0.f);
}

// ---------- transposed conv 3x3 stride2 pad1 outpad1; ACT: 0=relu, 1=sigmoid ----------
template<int ACT>
__global__ __launch_bounds__(256) void k_deconv(const float* __restrict__ in, const float* __restrict__ w,
    const float* __restrict__ bias, float* __restrict__ out,
    int Cin, int Hin, int Win, int Cout){
  int Hout = Hin*2, Wout = Win*2;
  int idx = blockIdx.x*256 + threadIdx.x;
  int total = Cout*Hout*Wout;
  if(idx >= total) return;
  int ox = idx % Wout; int t = idx / Wout; int oy = t % Hout; int oc = t / Hout;
  float acc = bias[oc];
  for(int ic=0; ic<Cin; ++ic){
    const float* ip = in + ic*Hin*Win;
    const float* wp = w + (ic*Cout + oc)*9;
    #pragma unroll
    for(int ky=0; ky<3; ++ky){
      int ty = oy + 1 - ky;
      if(ty < 0 || (ty & 1)) continue;
      int iy = ty >> 1;
      if(iy >= Hin) continue;
      const float* row = ip + iy*Win;
      #pragma unroll
      for(int kx=0; kx<3; ++kx){
        int tx = ox + 1 - kx;
        if(tx < 0 || (tx & 1)) continue;
        int ix = tx >> 1;
        if(ix < Win) acc += row[ix] * wp[ky*3+kx];
      }
    }
  }
  if(ACT == 0) out[idx] = fmaxf(acc, 0.f);
  else         out[idx] = 1.f/(1.f + __expf(-acc));
}

extern "C" void kernel_launch(void* const* d_in, const int* in_sizes, int n_in,
                              void* d_out, int out_size, void* d_ws, size_t ws_size,
                              hipStream_t stream){
  const float* X    = (const float*)d_in[0];
  const float* EPS  = (const float*)d_in[1];
  const float* c1w  = (const float*)d_in[2];  const float* c1b = (const float*)d_in[3];
  const float* q1w  = (const float*)d_in[4];  const float* q1b = (const float*)d_in[5];
  const float* k1w  = (const float*)d_in[6];  const float* k1b = (const float*)d_in[7];
  const float* v1w  = (const float*)d_in[8];  const float* v1b = (const float*)d_in[9];
  const float* g1   = (const float*)d_in[10];
  const float* c2w  = (const float*)d_in[11]; const float* c2b = (const float*)d_in[12];
  const float* q2w  = (const float*)d_in[13]; const float* q2b = (const float*)d_in[14];
  const float* k2w  = (const float*)d_in[15]; const float* k2b = (const float*)d_in[16];
  const float* v2w  = (const float*)d_in[17]; const float* v2b = (const float*)d_in[18];
  const float* g2   = (const float*)d_in[19];
  const float* c3w  = (const float*)d_in[20]; const float* c3b = (const float*)d_in[21];
  const float* fmw  = (const float*)d_in[22]; const float* fmb = (const float*)d_in[23];
  const float* flw  = (const float*)d_in[24]; const float* flb = (const float*)d_in[25];
  const float* fdw  = (const float*)d_in[26]; const float* fdb = (const float*)d_in[27];
  const float* d1w  = (const float*)d_in[28]; const float* d1b = (const float*)d_in[29];
  const float* d2w  = (const float*)d_in[30]; const float* d2b = (const float*)d_in[31];
  const float* d3w  = (const float*)d_in[32]; const float* d3b = (const float*)d_in[33];

  float* ws  = (float*)d_ws;
  float* h1  = ws;            // 401408   [32][112][112]
  float* h1a = h1  + 401408;  // 401408
  float* q1  = h1a + 401408;  // 50176    [12544][4]
  float* k1  = q1  + 50176;   // 50176    [4][12544]
  float* v1f = k1  + 50176;   // 401408 slot; holds bf16 [32][12544]
  float* h2  = v1f + 401408;  // 200704   [64][56][56]
  float* h2a = h2  + 200704;  // 200704
  float* q2  = h2a + 200704;  // 25088
  float* k2  = q2  + 25088;   // 25088
  float* v2f = k2  + 25088;   // 200704 slot; holds bf16 [64][3136]
  float* h3  = v2f + 200704;  // 100352   [128][28][28]
  float* pmu = h3  + 100352;  // 100352   (392 x 256)
  float* plv = pmu + 100352;  // 100352
  float* z   = plv + 100352;  // 256
  float* part= z   + 256;     // attn partial acc
  bf16* v1b_ = (bf16*)v1f;
  bf16* v2b_ = (bf16*)v2f;
  // decoder buffers alias dead encoder regions:
  float* dd0 = h1;            // 100352 (h1 dead after attn1 combine)
  float* dd1 = h1 + 100352;   // 200704
  float* dd2 = h1a;           // 401408 (h1a dead after conv2)

  const size_t base = 2258176;                 // floats up to 'part'
  const bool big = ws_size >= (base + 2809856 + 87808) * 4;  // NSPLIT=7 footprint
  float* pdn = part + (big ? 2809856 : 802816);

  float* OUT = (float*)d_out;   // [recon 150528 | mu 256 | logvar 256], all f32

  k_conv_s2<<<dim3(1568),dim3(256),0,stream>>>(X, c1w, c1b, h1, 3,224,224, 32,112,112);
  k_qkv<32,4,4><<<dim3(196),dim3(256),0,stream>>>(h1, q1w,q1b, k1w,k1b, v1w,v1b, q1,k1,v1b_, 12544);
  if(big){
    k_attn_mfma<32,4,128,7><<<dim3(1372),dim3(256),0,stream>>>(q1,k1,v1b_, part, pdn, 12544);
    k_attn_comb<32,7><<<dim3(1568),dim3(256),0,stream>>>(part, pdn, h1, g1, h1a, 12544);
  } else {
    k_attn_mfma<32,4,128,2><<<dim3(392),dim3(256),0,stream>>>(q1,k1,v1b_, part, pdn, 12544);
    k_attn_comb<32,2><<<dim3(1568),dim3(256),0,stream>>>(part, pdn, h1, g1, h1a, 12544);
  }
  k_conv_s2<<<dim3(784),dim3(256),0,stream>>>(h1a, c2w, c2b, h2, 32,112,112, 64,56,56);
  k_qkv<64,8,8><<<dim3(98),dim3(256),0,stream>>>(h2, q2w,q2b, k2w,k2b, v2w,v2b, q2,k2,v2b_, 3136);
  if(big){
    k_attn_mfma<64,8,64,7><<<dim3(343),dim3(256),0,stream>>>(q2,k2,v2b_, part, pdn, 3136);
    k_attn_comb<64,7><<<dim3(784),dim3(256),0,stream>>>(part, pdn, h2, g2, h2a, 3136);
  } else {
    k_attn_mfma<64,8,64,1><<<dim3(49),dim3(256),0,stream>>>(q2,k2,v2b_, part, pdn, 3136);
    k_attn_comb<64,1><<<dim3(784),dim3(256),0,stream>>>(part, pdn, h2, g2, h2a, 3136);
  }
  k_conv_s2<<<dim3(392),dim3(256),0,stream>>>(h2a, c3w, c3b, h3, 64,56,56, 128,28,28);
  k_fc2_part<<<dim3(392),dim3(128),0,stream>>>(h3, fmw, flw, pmu, plv);
  k_reparam<<<dim3(1),dim3(256),0,stream>>>(pmu, plv, fmb, flb, EPS, z, OUT+150528, OUT+150784);
  k_fc_dec<<<dim3(196),dim3(256),0,stream>>>(z, fdw, fdb, dd0);
  k_deconv<0><<<dim3(784),dim3(256),0,stream>>>(dd0, d1w, d1b, dd1, 128,28,28, 64);
  k_deconv<0><<<dim3(1568),dim3(256),0,stream>>>(dd1, d2w, d2b, dd2, 64,56,56, 32);
  k_deconv<1><<<dim3(588),dim3(256),0,stream>>>(dd2, d3w, d3b, OUT, 32,112,112, 3);
}

// Round 7
// 460.491 us; speedup vs baseline: 2.5765x; 1.4442x over previous
//
#include <hip/hip_runtime.h>
#include <hip/hip_bf16.h>

typedef __hip_bfloat16 bf16;
typedef __attribute__((ext_vector_type(8))) short short8v;   // 8 x bf16 (4 VGPR) MFMA frag
typedef __attribute__((ext_vector_type(4))) float f32x4;

__device__ __forceinline__ unsigned int f2b(float f){        // f32 -> bf16 bits, RNE
  unsigned int u = __float_as_uint(f);
  return (u + 0x7fffu + ((u>>16)&1u)) >> 16;
}
__device__ __forceinline__ unsigned int pkbf(float lo, float hi){ return f2b(lo) | (f2b(hi)<<16); }

// ---------- conv 3x3 stride2 pad1 + relu ----------
__global__ __launch_bounds__(256) void k_conv_s2(const float* __restrict__ in, const float* __restrict__ w,
    const float* __restrict__ bias, float* __restrict__ out,
    int Cin, int Hin, int Win, int Cout, int Hout, int Wout){
  int idx = blockIdx.x*256 + threadIdx.x;
  int total = Cout*Hout*Wout;
  if(idx >= total) return;
  int ox = idx % Wout; int t = idx / Wout; int oy = t % Hout; int oc = t / Hout;
  float acc = bias[oc];
  int iy0 = oy*2 - 1, ix0 = ox*2 - 1;
  for(int ic=0; ic<Cin; ++ic){
    const float* ip = in + ic*Hin*Win;
    const float* wp = w + (oc*Cin + ic)*9;
    #pragma unroll
    for(int ky=0; ky<3; ++ky){
      int iy = iy0 + ky;
      if((unsigned)iy >= (unsigned)Hin) continue;
      const float* row = ip + iy*Win;
      #pragma unroll
      for(int kx=0; kx<3; ++kx){
        int ix = ix0 + kx;
        if((unsigned)ix < (unsigned)Win) acc += row[ix] * wp[ky*3+kx];
      }
    }
  }
  out[idx] = fmaxf(acc, 0.f);
}

// ---------- q/k/v projections, TPN threads per token; v stored bf16 ----------
template<int C, int O, int TPN>
__global__ __launch_bounds__(256) void k_qkv(const float* __restrict__ x,  // [C][N]
    const float* __restrict__ wq, const float* __restrict__ bq,
    const float* __restrict__ wk, const float* __restrict__ bk,
    const float* __restrict__ wv, const float* __restrict__ bv,
    float* __restrict__ q,  // [N][O]
    float* __restrict__ k,  // [O][N]
    bf16* __restrict__ v,   // [C][N] bf16
    int N){
  constexpr int NPB = 256/TPN;
  constexpr int OP = O/TPN > 0 ? O/TPN : 1;
  constexpr int CP = C/TPN;
  const int n = blockIdx.x*NPB + threadIdx.x/TPN;
  const int p = threadIdx.x%TPN;
  float xc[C];
  #pragma unroll
  for(int c=0;c<C;++c) xc[c] = x[c*N+n];
  #pragma unroll
  for(int oo=0;oo<OP;++oo){
    int o = p*OP + oo;
    float aq = bq[o], ak = bk[o];
    #pragma unroll
    for(int c=0;c<C;++c){ aq += wq[o*C+c]*xc[c]; ak += wk[o*C+c]*xc[c]; }
    q[n*O+o] = aq;
    k[o*N+n] = ak;
  }
  #pragma unroll
  for(int cc=0;cc<CP;++cc){
    int o = p*CP + cc;
    float av = bv[o];
    #pragma unroll
    for(int c=0;c<C;++c) av += wv[o*C+c]*xc[c];
    v[o*N+n] = __float2bfloat16(av);
  }
}

// ---------- MFMA flash attention, partial (key-split) ----------
template<int C, int O, int ST, int NSPLIT>
__global__ __launch_bounds__(256) void k_attn_mfma(
    const float* __restrict__ q, const float* __restrict__ kk, const bf16* __restrict__ vb,
    float* __restrict__ pacc, float* __restrict__ pden, int N){
  constexpr int NT = C/16;
  constexpr int OF4 = O/4;
  constexpr int VROW = ST*2 + 16;        // bytes; word-stride % 32 == 4
  __shared__ __align__(16) char vsm[C*VROW];
  __shared__ float4 ksm4[ST*OF4];        // xor-swizzled rows of O floats
  const int tid = threadIdx.x;
  const int qblk = blockIdx.x / NSPLIT, split = blockIdx.x % NSPLIT;
  const int KEYS = N / NSPLIT;
  const int kbase = split * KEYS;
  const int wv = tid >> 6;
  const int l  = tid & 63;
  const int lg = l >> 4, lq = l & 15;
  const int mq = qblk*64 + wv*16 + lq;
  float qv[O];
  #pragma unroll
  for(int o=0;o<O;++o) qv[o] = q[mq*O+o];
  f32x4 acc[NT];
  #pragma unroll
  for(int nt=0;nt<NT;++nt) acc[nt] = (f32x4){0.f,0.f,0.f,0.f};
  float den = 0.f;

  for(int g0=0; g0<KEYS; g0+=ST){
    __syncthreads();
    for(int j=tid; j<ST; j+=256){
      int jj = j ^ ((j>>3)&7);
      #pragma unroll
      for(int h=0;h<OF4;++h){
        float4 kv;
        ((float*)&kv)[0] = kk[(h*4+0)*N + kbase + g0 + j];
        ((float*)&kv)[1] = kk[(h*4+1)*N + kbase + g0 + j];
        ((float*)&kv)[2] = kk[(h*4+2)*N + kbase + g0 + j];
        ((float*)&kv)[3] = kk[(h*4+3)*N + kbase + g0 + j];
        ksm4[jj*OF4 + h] = kv;
      }
    }
    for(int ch=tid; ch < C*(ST/8); ch += 256){
      int c = ch / (ST/8), j8 = ch % (ST/8);
      *(uint4*)(vsm + c*VROW + j8*16) =
          *(const uint4*)(vb + (size_t)c*N + kbase + g0 + j8*8);
    }
    __syncthreads();
    #pragma unroll
    for(int s=0; s<ST/32; ++s){
      union { unsigned int u[4]; short8v s8; } pa;
      float dl = 0.f;
      #pragma unroll
      for(int u=0; u<4; ++u){
        float pr[2];
        #pragma unroll
        for(int hh=0; hh<2; ++hh){
          int key = s*32 + lg*8 + u*2 + hh;
          int kr = key ^ ((key>>3)&7);
          float sc = 0.f;
          #pragma unroll
          for(int h=0;h<OF4;++h){
            float4 k4 = ksm4[kr*OF4 + h];
            sc += qv[h*4+0]*k4.x + qv[h*4+1]*k4.y + qv[h*4+2]*k4.z + qv[h*4+3]*k4.w;
          }
          pr[hh] = __expf(sc);
          dl += pr[hh];
        }
        pa.u[u] = pkbf(pr[0], pr[1]);
      }
      den += dl;
      #pragma unroll
      for(int nt=0; nt<NT; ++nt){
        short8v bf_ = *(const short8v*)(vsm + (lq + nt*16)*VROW + (s*32 + lg*8)*2);
        acc[nt] = __builtin_amdgcn_mfma_f32_16x16x32_bf16(pa.s8, bf_, acc[nt], 0,0,0);
      }
    }
  }
  den += __shfl_xor(den, 16);
  den += __shfl_xor(den, 32);
  if(lg == 0) pden[(size_t)split*N + qblk*64 + wv*16 + lq] = den;
  #pragma unroll
  for(int nt=0; nt<NT; ++nt){
    #pragma unroll
    for(int r=0;r<4;++r){
      int qg = qblk*64 + wv*16 + lg*4 + r;       // C/D: row=(l>>4)*4+r, col=l&15
      pacc[((size_t)split*N + qg)*C + nt*16 + lq] = acc[nt][r];
    }
  }
}

// ---------- attention combine: out = gamma * (sum acc)/(sum den) + xin ----------
template<int C, int NSPLIT>
__global__ __launch_bounds__(256) void k_attn_comb(const float* __restrict__ pacc, const float* __restrict__ pden,
    const float* __restrict__ xin, const float* __restrict__ gamma, float* __restrict__ out, int N){
  int idx = blockIdx.x*256 + threadIdx.x;
  if(idx >= N*C) return;
  int c = idx / N, m = idx - c*N;
  float a = 0.f, d = 0.f;
  #pragma unroll
  for(int s=0;s<NSPLIT;++s){
    a += pacc[((size_t)s*N + m)*C + c];
    d += pden[(size_t)s*N + m];
  }
  out[idx] = gamma[0]*a/d + xin[idx];
}

// ---------- fc_mu / fc_lv partial sums (chunk of 256 features per block) ----------
__global__ __launch_bounds__(128) void k_fc2_part(const float* __restrict__ hf,
    const float* __restrict__ wmu, const float* __restrict__ wlv,
    float* __restrict__ pmu, float* __restrict__ plv){
  __shared__ float sh[256];
  const int t = threadIdx.x;
  const int f0 = blockIdx.x * 256;
  for(int i=t; i<256; i+=128) sh[i] = hf[f0+i];
  __syncthreads();
  float a0=0.f, a1=0.f, c0=0.f, c1=0.f;
  const float2* wm = (const float2*)wmu + (size_t)f0*128 + t;
  const float2* wl = (const float2*)wlv + (size_t)f0*128 + t;
  for(int j=0;j<256;++j){
    float h = sh[j];
    float2 um = wm[(size_t)j*128];
    float2 ul = wl[(size_t)j*128];
    a0 += h*um.x; a1 += h*um.y;
    c0 += h*ul.x; c1 += h*ul.y;
  }
  pmu[blockIdx.x*256 + 2*t]   = a0;
  pmu[blockIdx.x*256 + 2*t+1] = a1;
  plv[blockIdx.x*256 + 2*t]   = c0;
  plv[blockIdx.x*256 + 2*t+1] = c1;
}

// ---------- reduce partials + bias + reparametrize; emit mu/logvar (f32) ----------
__global__ __launch_bounds__(256) void k_reparam(const float* __restrict__ pmu, const float* __restrict__ plv,
    const float* __restrict__ bmu, const float* __restrict__ blv, const float* __restrict__ eps,
    float* __restrict__ z, float* __restrict__ omu, float* __restrict__ olv){
  const int o = threadIdx.x;
  float mu = bmu[o], lv = blv[o];
  for(int i=0;i<392;++i){ mu += pmu[i*256+o]; lv += plv[i*256+o]; }
  float zz = mu + eps[o] * expf(0.5f*lv);
  z[o] = zz;
  omu[o] = mu;
  olv[o] = lv;
}

// ---------- decoder fc: d = relu(z @ W + b), W [256][100352] ----------
__global__ __launch_bounds__(256) void k_fc_dec(const float* __restrict__ z, const float* __restrict__ w,
    const float* __restrict__ b, float* __restrict__ out){
  __shared__ float sz[256];
  const int t = threadIdx.x;
  sz[t] = z[t];
  __syncthreads();
  const int f2 = blockIdx.x*256 + t;
  float a0 = b[2*f2], a1 = b[2*f2+1];
  const float2* wp = (const float2*)w + f2;
  for(int o=0;o<256;++o){
    float2 u = wp[(size_t)o*50176];
    a0 += sz[o]*u.x; a1 += sz[o]*u.y;
  }
  out[2*f2]   = fmaxf(a0, 0.f);
  out[2*f2+1] = fmaxf(a1, 0.f);
}

// ---------- transposed conv 3x3 s2 p1 op1, parity-decomposed ----------
// Output (2qy+py, 2qx+px); taps fixed per parity (ty=oy+1-ky parity rules):
// (0,0): w4@in(qy,qx) | (0,1): w5@(qy,qx), w3@(qy,qx+1) | (1,0): w7@(qy,qx), w1@(qy+1,qx)
// (1,1): w8@(qy,qx), w6@(qy,qx+1), w2@(qy+1,qx), w0@(qy+1,qx+1)
// blockIdx.y = oc -> weights [CIN][9] staged in LDS once; branch-free unrolled ic loop.
template<int CIN, int COUT, int ACT>
__global__ __launch_bounds__(256) void k_deconv_p(const float* __restrict__ in, const float* __restrict__ w,
    const float* __restrict__ bias, float* __restrict__ out, int Hin, int Win){
  __shared__ float wl[CIN*9];
  const int oc = blockIdx.y;
  const int tid = threadIdx.x;
  for(int i=tid; i<CIN*9; i+=256) wl[i] = w[((i/9)*COUT + oc)*9 + (i%9)];
  __syncthreads();
  const int nq = Hin*Win;
  const int code = blockIdx.x*256 + tid;
  if(code >= 4*nq) return;
  const int q = code % nq;
  const int pcode = code / nq;          // wave-uniform except at nq boundaries
  const int px = pcode & 1, py = pcode >> 1;
  const int qy = q / Win, qx = q - qy*Win;
  const float m1x = (qx+1 < Win) ? 1.f : 0.f;
  const float m1y = (qy+1 < Hin) ? 1.f : 0.f;
  const int qxc = (qx+1 < Win) ? qx+1 : qx;
  const int qyc = (qy+1 < Hin) ? qy+1 : qy;
  const int o00 = qy*Win+qx, o01 = qy*Win+qxc, o10 = qyc*Win+qx, o11 = qyc*Win+qxc;
  const int HW = nq;
  float acc = bias[oc];
  if(pcode == 0){
    #pragma unroll 4
    for(int ic=0; ic<CIN; ++ic) acc += in[ic*HW + o00] * wl[ic*9+4];
  } else if(pcode == 1){
    #pragma unroll 4
    for(int ic=0; ic<CIN; ++ic){
      acc += in[ic*HW + o00] * wl[ic*9+5];
      acc += (in[ic*HW + o01]*m1x) * wl[ic*9+3];
    }
  } else if(pcode == 2){
    #pragma unroll 4
    for(int ic=0; ic<CIN; ++ic){
      acc += in[ic*HW + o00] * wl[ic*9+7];
      acc += (in[ic*HW + o10]*m1y) * wl[ic*9+1];
    }
  } else {
    #pragma unroll 4
    for(int ic=0; ic<CIN; ++ic){
      acc += in[ic*HW + o00] * wl[ic*9+8];
      acc += (in[ic*HW + o01]*m1x) * wl[ic*9+6];
      acc += (in[ic*HW + o10]*m1y) * wl[ic*9+2];
      acc += (in[ic*HW + o11]*(m1x*m1y)) * wl[ic*9+0];
    }
  }
  const int oy = 2*qy+py, ox = 2*qx+px;
  float r = (ACT==0) ? fmaxf(acc, 0.f) : 1.f/(1.f + __expf(-acc));
  out[(oc*2*Hin + oy)*2*Win + ox] = r;
}

extern "C" void kernel_launch(void* const* d_in, const int* in_sizes, int n_in,
                              void* d_out, int out_size, void* d_ws, size_t ws_size,
                              hipStream_t stream){
  const float* X    = (const float*)d_in[0];
  const float* EPS  = (const float*)d_in[1];
  const float* c1w  = (const float*)d_in[2];  const float* c1b = (const float*)d_in[3];
  const float* q1w  = (const float*)d_in[4];  const float* q1b = (const float*)d_in[5];
  const float* k1w  = (const float*)d_in[6];  const float* k1b = (const float*)d_in[7];
  const float* v1w  = (const float*)d_in[8];  const float* v1b = (const float*)d_in[9];
  const float* g1   = (const float*)d_in[10];
  const float* c2w  = (const float*)d_in[11]; const float* c2b = (const float*)d_in[12];
  const float* q2w  = (const float*)d_in[13]; const float* q2b = (const float*)d_in[14];
  const float* k2w  = (const float*)d_in[15]; const float* k2b = (const float*)d_in[16];
  const float* v2w  = (const float*)d_in[17]; const float* v2b = (const float*)d_in[18];
  const float* g2   = (const float*)d_in[19];
  const float* c3w  = (const float*)d_in[20]; const float* c3b = (const float*)d_in[21];
  const float* fmw  = (const float*)d_in[22]; const float* fmb = (const float*)d_in[23];
  const float* flw  = (const float*)d_in[24]; const float* flb = (const float*)d_in[25];
  const float* fdw  = (const float*)d_in[26]; const float* fdb = (const float*)d_in[27];
  const float* d1w  = (const float*)d_in[28]; const float* d1b = (const float*)d_in[29];
  const float* d2w  = (const float*)d_in[30]; const float* d2b = (const float*)d_in[31];
  const float* d3w  = (const float*)d_in[32]; const float* d3b = (const float*)d_in[33];

  float* ws  = (float*)d_ws;
  float* h1  = ws;            // 401408   [32][112][112]
  float* h1a = h1  + 401408;  // 401408
  float* q1  = h1a + 401408;  // 50176    [12544][4]
  float* k1  = q1  + 50176;   // 50176    [4][12544]
  float* v1f = k1  + 50176;   // 401408 slot; holds bf16 [32][12544]
  float* h2  = v1f + 401408;  // 200704   [64][56][56]
  float* h2a = h2  + 200704;  // 200704
  float* q2  = h2a + 200704;  // 25088
  float* k2  = q2  + 25088;   // 25088
  float* v2f = k2  + 25088;   // 200704 slot; holds bf16 [64][3136]
  float* h3  = v2f + 200704;  // 100352   [128][28][28]
  float* pmu = h3  + 100352;  // 100352   (392 x 256)
  float* plv = pmu + 100352;  // 100352
  float* z   = plv + 100352;  // 256
  float* part= z   + 256;     // attn partial acc
  bf16* v1b_ = (bf16*)v1f;
  bf16* v2b_ = (bf16*)v2f;
  // decoder buffers alias dead encoder regions:
  float* dd0 = h1;            // 100352 (h1 dead after attn1 combine)
  float* dd1 = h1 + 100352;   // 200704
  float* dd2 = h1a;           // 401408 (h1a dead after conv2)

  const size_t base = 2258176;                 // floats up to 'part'
  const bool big = ws_size >= (base + 2809856 + 87808) * 4;  // NSPLIT=7 footprint
  float* pdn = part + (big ? 2809856 : 802816);

  float* OUT = (float*)d_out;   // [recon 150528 | mu 256 | logvar 256], all f32

  k_conv_s2<<<dim3(1568),dim3(256),0,stream>>>(X, c1w, c1b, h1, 3,224,224, 32,112,112);
  k_qkv<32,4,4><<<dim3(196),dim3(256),0,stream>>>(h1, q1w,q1b, k1w,k1b, v1w,v1b, q1,k1,v1b_, 12544);
  if(big){
    k_attn_mfma<32,4,128,7><<<dim3(1372),dim3(256),0,stream>>>(q1,k1,v1b_, part, pdn, 12544);
    k_attn_comb<32,7><<<dim3(1568),dim3(256),0,stream>>>(part, pdn, h1, g1, h1a, 12544);
  } else {
    k_attn_mfma<32,4,128,2><<<dim3(392),dim3(256),0,stream>>>(q1,k1,v1b_, part, pdn, 12544);
    k_attn_comb<32,2><<<dim3(1568),dim3(256),0,stream>>>(part, pdn, h1, g1, h1a, 12544);
  }
  k_conv_s2<<<dim3(784),dim3(256),0,stream>>>(h1a, c2w, c2b, h2, 32,112,112, 64,56,56);
  k_qkv<64,8,8><<<dim3(98),dim3(256),0,stream>>>(h2, q2w,q2b, k2w,k2b, v2w,v2b, q2,k2,v2b_, 3136);
  if(big){
    k_attn_mfma<64,8,64,7><<<dim3(343),dim3(256),0,stream>>>(q2,k2,v2b_, part, pdn, 3136);
    k_attn_comb<64,7><<<dim3(784),dim3(256),0,stream>>>(part, pdn, h2, g2, h2a, 3136);
  } else {
    k_attn_mfma<64,8,64,1><<<dim3(49),dim3(256),0,stream>>>(q2,k2,v2b_, part, pdn, 3136);
    k_attn_comb<64,1><<<dim3(784),dim3(256),0,stream>>>(part, pdn, h2, g2, h2a, 3136);
  }
  k_conv_s2<<<dim3(392),dim3(256),0,stream>>>(h2a, c3w, c3b, h3, 64,56,56, 128,28,28);
  k_fc2_part<<<dim3(392),dim3(128),0,stream>>>(h3, fmw, flw, pmu, plv);
  k_reparam<<<dim3(1),dim3(256),0,stream>>>(pmu, plv, fmb, flb, EPS, z, OUT+150528, OUT+150784);
  k_fc_dec<<<dim3(196),dim3(256),0,stream>>>(z, fdw, fdb, dd0);
  k_deconv_p<128,64,0><<<dim3(13,64),dim3(256),0,stream>>>(dd0, d1w, d1b, dd1, 28,28);
  k_deconv_p<64,32,0><<<dim3(49,32),dim3(256),0,stream>>>(dd1, d2w, d2b, dd2, 56,56);
  k_deconv_p<32,3,1><<<dim3(196,3),dim3(256),0,stream>>>(dd2, d3w, d3b, OUT, 112,112);
}

// Round 8
// 458.782 us; speedup vs baseline: 2.5861x; 1.0037x over previous
//
#include <hip/hip_runtime.h>
#include <hip/hip_bf16.h>

typedef __hip_bfloat16 bf16;
typedef __attribute__((ext_vector_type(8))) short short8v;   // 8 x bf16 (4 VGPR) MFMA frag
typedef __attribute__((ext_vector_type(4))) float f32x4;

__device__ __forceinline__ unsigned int cvtpk(float lo, float hi){
  unsigned int r;
  asm volatile("v_cvt_pk_bf16_f32 %0, %1, %2" : "=v"(r) : "v"(lo), "v"(hi));
  return r;
}

// ---------- conv 3x3 stride2 pad1 + relu; per-oc block, LDS weights, branch-free ----------
// s2/p1 with even output: only iy=-1 (oy=0) / ix=-1 (ox=0) are OOB -> clamp + mask.
template<int CIN>
__global__ __launch_bounds__(256) void k_conv_s2t(const float* __restrict__ in, const float* __restrict__ w,
    const float* __restrict__ bias, float* __restrict__ out, int Hin, int Win){
  const int Hout = Hin>>1, Wout = Win>>1, HW = Hout*Wout;
  __shared__ float wl[CIN*9];
  const int oc = blockIdx.y, tid = threadIdx.x;
  for(int i=tid;i<CIN*9;i+=256) wl[i] = w[oc*CIN*9 + i];
  __syncthreads();
  const int idx = blockIdx.x*256 + tid;
  if(idx >= HW) return;
  const int oy = idx/Wout, ox = idx - oy*Wout;
  const int iy0 = 2*oy-1, ix0 = 2*ox-1;
  const float mt = iy0>=0 ? 1.f:0.f, ml = ix0>=0 ? 1.f:0.f;
  const int iyc = iy0<0?0:iy0, ixc = ix0<0?0:ix0;
  const int x1 = ix0+1, x2 = ix0+2;
  float acc = bias[oc];
  #pragma unroll 4
  for(int ic=0; ic<CIN; ++ic){
    const float* b0 = in + (ic*Hin + iyc )*Win;
    const float* b1 = in + (ic*Hin + iy0+1)*Win;
    const float* b2 = in + (ic*Hin + iy0+2)*Win;
    const float* wp = wl + ic*9;
    float t00 = b0[ixc]*(mt*ml), t01 = b0[x1]*mt, t02 = b0[x2]*mt;
    float t10 = b1[ixc]*ml,      t11 = b1[x1],    t12 = b1[x2];
    float t20 = b2[ixc]*ml,      t21 = b2[x1],    t22 = b2[x2];
    acc += t00*wp[0]+t01*wp[1]+t02*wp[2]
         + t10*wp[3]+t11*wp[4]+t12*wp[5]
         + t20*wp[6]+t21*wp[7]+t22*wp[8];
  }
  out[oc*HW + idx] = fmaxf(acc, 0.f);
}

// ---------- q/k/v projections, TPN threads per token; v stored bf16 ----------
template<int C, int O, int TPN>
__global__ __launch_bounds__(256) void k_qkv(const float* __restrict__ x,  // [C][N]
    const float* __restrict__ wq, const float* __restrict__ bq,
    const float* __restrict__ wk, const float* __restrict__ bk,
    const float* __restrict__ wv, const float* __restrict__ bv,
    float* __restrict__ q,  // [N][O]
    float* __restrict__ k,  // [O][N]
    bf16* __restrict__ v,   // [C][N] bf16
    int N){
  constexpr int NPB = 256/TPN;
  constexpr int OP = O/TPN > 0 ? O/TPN : 1;
  constexpr int CP = C/TPN;
  const int n = blockIdx.x*NPB + threadIdx.x/TPN;
  const int p = threadIdx.x%TPN;
  float xc[C];
  #pragma unroll
  for(int c=0;c<C;++c) xc[c] = x[c*N+n];
  #pragma unroll
  for(int oo=0;oo<OP;++oo){
    int o = p*OP + oo;
    float aq = bq[o], ak = bk[o];
    #pragma unroll
    for(int c=0;c<C;++c){ aq += wq[o*C+c]*xc[c]; ak += wk[o*C+c]*xc[c]; }
    q[n*O+o] = aq;
    k[o*N+n] = ak;
  }
  #pragma unroll
  for(int cc=0;cc<CP;++cc){
    int o = p*CP + cc;
    float av = bv[o];
    #pragma unroll
    for(int c=0;c<C;++c) av += wv[o*C+c]*xc[c];
    v[o*N+n] = __float2bfloat16(av);
  }
}

// ---------- MFMA flash attention, partial (key-split), QG query-groups/wave ----------
// Wave = 16*QG queries; lane l: scores for queries (g*16 + l&15), keys (l>>4)*8..+7 per
// 32-slice. K rows padded (row = j + (j>>3)): in-loop LDS addr = lg*9 + const (bank-clean).
// exp -> v_cvt_pk_bf16_f32 -> A-frag; V bf16 rows, B-frag = ds_read_b128 (shared over QG).
template<int C, int O, int ST, int NSPLIT, int QG>
__global__ __launch_bounds__(256) void k_attn_mfma(
    const float* __restrict__ q, const float* __restrict__ kk, const bf16* __restrict__ vb,
    float* __restrict__ pacc, float* __restrict__ pden, int N){
  constexpr int NT = C/16;
  constexpr int OF4 = O/4;
  constexpr int VROW = ST*2 + 16;        // bytes
  __shared__ __align__(16) char vsm[C*VROW];
  __shared__ float4 ksm4[(ST + ST/8)*OF4];
  const int tid = threadIdx.x;
  const int qblk = blockIdx.x / NSPLIT, split = blockIdx.x % NSPLIT;
  const int KEYS = N / NSPLIT;
  const int kbase = split * KEYS;
  const int wv = tid >> 6;
  const int l  = tid & 63;
  const int lg = l >> 4, lq = l & 15;
  const int qbase = qblk*(64*QG) + wv*(16*QG);
  float qv[QG][O];
  #pragma unroll
  for(int g=0; g<QG; ++g)
    #pragma unroll
    for(int o=0;o<O;++o) qv[g][o] = q[(qbase + g*16 + lq)*O + o];
  f32x4 acc[QG][NT];
  #pragma unroll
  for(int g=0; g<QG; ++g)
    #pragma unroll
    for(int nt=0;nt<NT;++nt) acc[g][nt] = (f32x4){0.f,0.f,0.f,0.f};
  float den[QG];
  #pragma unroll
  for(int g=0; g<QG; ++g) den[g] = 0.f;

  for(int g0=0; g0<KEYS; g0+=ST){
    __syncthreads();
    for(int j=tid; j<ST; j+=256){
      int row = j + (j>>3);
      #pragma unroll
      for(int h=0;h<OF4;++h){
        float4 kv;
        ((float*)&kv)[0] = kk[(h*4+0)*N + kbase + g0 + j];
        ((float*)&kv)[1] = kk[(h*4+1)*N + kbase + g0 + j];
        ((float*)&kv)[2] = kk[(h*4+2)*N + kbase + g0 + j];
        ((float*)&kv)[3] = kk[(h*4+3)*N + kbase + g0 + j];
        ksm4[row*OF4 + h] = kv;
      }
    }
    for(int ch=tid; ch < C*(ST/8); ch += 256){
      int c = ch / (ST/8), j8 = ch % (ST/8);
      *(uint4*)(vsm + c*VROW + j8*16) =
          *(const uint4*)(vb + (size_t)c*N + kbase + g0 + j8*8);
    }
    __syncthreads();
    #pragma unroll
    for(int s=0; s<ST/32; ++s){
      float pr[QG][8];
      #pragma unroll
      for(int e=0; e<8; ++e){
        const int row = s*36 + lg*9 + e;        // padded index; e folds to ds offset
        #pragma unroll
        for(int g=0; g<QG; ++g){
          float sc = 0.f;
          #pragma unroll
          for(int h=0;h<OF4;++h){
            float4 k4 = ksm4[row*OF4 + h];
            sc += qv[g][h*4+0]*k4.x + qv[g][h*4+1]*k4.y + qv[g][h*4+2]*k4.z + qv[g][h*4+3]*k4.w;
          }
          pr[g][e] = __expf(sc);
        }
      }
      union { unsigned int u[4]; short8v s8; } pa[QG];
      #pragma unroll
      for(int g=0; g<QG; ++g){
        #pragma unroll
        for(int u=0; u<4; ++u) pa[g].u[u] = cvtpk(pr[g][2*u], pr[g][2*u+1]);
        #pragma unroll
        for(int e=0; e<8; ++e) den[g] += pr[g][e];
      }
      #pragma unroll
      for(int nt=0; nt<NT; ++nt){
        short8v bf_ = *(const short8v*)(vsm + (lq + nt*16)*VROW + (s*32 + lg*8)*2);
        #pragma unroll
        for(int g=0; g<QG; ++g)
          acc[g][nt] = __builtin_amdgcn_mfma_f32_16x16x32_bf16(pa[g].s8, bf_, acc[g][nt], 0,0,0);
      }
    }
  }
  #pragma unroll
  for(int g=0; g<QG; ++g){
    den[g] += __shfl_xor(den[g], 16);
    den[g] += __shfl_xor(den[g], 32);
    if(lg == 0) pden[(size_t)split*N + qbase + g*16 + lq] = den[g];
  }
  #pragma unroll
  for(int g=0; g<QG; ++g)
    #pragma unroll
    for(int nt=0; nt<NT; ++nt)
      #pragma unroll
      for(int r=0;r<4;++r){
        int qg_ = qbase + g*16 + lg*4 + r;      // C/D: row=(l>>4)*4+r, col=l&15
        pacc[((size_t)split*N + qg_)*C + nt*16 + lq] = acc[g][nt][r];
      }
}

// ---------- attention combine: out = gamma * (sum acc)/(sum den) + xin ----------
template<int C, int NSPLIT>
__global__ __launch_bounds__(256) void k_attn_comb(const float* __restrict__ pacc, const float* __restrict__ pden,
    const float* __restrict__ xin, const float* __restrict__ gamma, float* __restrict__ out, int N){
  int idx = blockIdx.x*256 + threadIdx.x;
  if(idx >= N*C) return;
  int c = idx / N, m = idx - c*N;
  float a = 0.f, d = 0.f;
  #pragma unroll
  for(int s=0;s<NSPLIT;++s){
    a += pacc[((size_t)s*N + m)*C + c];
    d += pden[(size_t)s*N + m];
  }
  out[idx] = gamma[0]*a/d + xin[idx];
}

// ---------- fc_mu / fc_lv partials: 784 blocks x 128-feature chunk; transposed output ----------
__global__ __launch_bounds__(256) void k_fc2_part(const float* __restrict__ hf,
    const float* __restrict__ wmu, const float* __restrict__ wlv,
    float* __restrict__ pmu, float* __restrict__ plv){
  __shared__ float sh[128];
  const int t = threadIdx.x, blk = blockIdx.x, f0 = blk*128;
  if(t < 128) sh[t] = hf[f0+t];
  __syncthreads();
  const int tp = t & 127;
  const float* wsel = (t<128) ? wmu : wlv;
  float*       dsel = (t<128) ? pmu : plv;
  const float2* wp = (const float2*)wsel + (size_t)f0*128 + tp;
  float a0=0.f, a1=0.f;
  #pragma unroll 4
  for(int j=0;j<128;++j){
    float h = sh[j];
    float2 u = wp[(size_t)j*128];
    a0 += h*u.x; a1 += h*u.y;
  }
  dsel[(2*tp)*784 + blk]   = a0;
  dsel[(2*tp+1)*784 + blk] = a1;
}

// ---------- reduce partials + bias + reparametrize; emit mu/logvar (f32) ----------
__global__ __launch_bounds__(256) void k_reparam(const float* __restrict__ pmu, const float* __restrict__ plv,
    const float* __restrict__ bmu, const float* __restrict__ blv, const float* __restrict__ eps,
    float* __restrict__ z, float* __restrict__ omu, float* __restrict__ olv){
  const int o = threadIdx.x;
  const float4* pm = (const float4*)(pmu + (size_t)o*784);
  const float4* pl = (const float4*)(plv + (size_t)o*784);
  float mu = bmu[o], lv = blv[o];
  #pragma unroll 4
  for(int i=0;i<196;++i){
    float4 a = pm[i]; mu += a.x+a.y+a.z+a.w;
    float4 b = pl[i]; lv += b.x+b.y+b.z+b.w;
  }
  float zz = mu + eps[o] * expf(0.5f*lv);
  z[o] = zz;
  omu[o] = mu;
  olv[o] = lv;
}

// ---------- decoder fc: d = relu(z @ W + b), W [256][100352]; 1 output/thread ----------
__global__ __launch_bounds__(256) void k_fc_dec(const float* __restrict__ z, const float* __restrict__ w,
    const float* __restrict__ b, float* __restrict__ out){
  __shared__ float sz[256];
  const int t = threadIdx.x;
  sz[t] = z[t];
  __syncthreads();
  const int f = blockIdx.x*256 + t;
  float a = b[f];
  #pragma unroll 4
  for(int o=0;o<256;++o) a += sz[o]*w[(size_t)o*100352 + f];
  out[f] = fmaxf(a, 0.f);
}

// ---------- transposed conv 3x3 s2 p1 op1, parity-decomposed ----------
template<int CIN, int COUT, int ACT>
__global__ __launch_bounds__(256) void k_deconv_p(const float* __restrict__ in, const float* __restrict__ w,
    const float* __restrict__ bias, float* __restrict__ out, int Hin, int Win){
  __shared__ float wl[CIN*9];
  const int oc = blockIdx.y;
  const int tid = threadIdx.x;
  for(int i=tid; i<CIN*9; i+=256) wl[i] = w[((i/9)*COUT + oc)*9 + (i%9)];
  __syncthreads();
  const int nq = Hin*Win;
  const int code = blockIdx.x*256 + tid;
  if(code >= 4*nq) return;
  const int q = code % nq;
  const int pcode = code / nq;
  const int px = pcode & 1, py = pcode >> 1;
  const int qy = q / Win, qx = q - qy*Win;
  const float m1x = (qx+1 < Win) ? 1.f : 0.f;
  const float m1y = (qy+1 < Hin) ? 1.f : 0.f;
  const int qxc = (qx+1 < Win) ? qx+1 : qx;
  const int qyc = (qy+1 < Hin) ? qy+1 : qy;
  const int o00 = qy*Win+qx, o01 = qy*Win+qxc, o10 = qyc*Win+qx, o11 = qyc*Win+qxc;
  const int HW = nq;
  float acc = bias[oc];
  if(pcode == 0){
    #pragma unroll 4
    for(int ic=0; ic<CIN; ++ic) acc += in[ic*HW + o00] * wl[ic*9+4];
  } else if(pcode == 1){
    #pragma unroll 4
    for(int ic=0; ic<CIN; ++ic){
      acc += in[ic*HW + o00] * wl[ic*9+5];
      acc += (in[ic*HW + o01]*m1x) * wl[ic*9+3];
    }
  } else if(pcode == 2){
    #pragma unroll 4
    for(int ic=0; ic<CIN; ++ic){
      acc += in[ic*HW + o00] * wl[ic*9+7];
      acc += (in[ic*HW + o10]*m1y) * wl[ic*9+1];
    }
  } else {
    #pragma unroll 4
    for(int ic=0; ic<CIN; ++ic){
      acc += in[ic*HW + o00] * wl[ic*9+8];
      acc += (in[ic*HW + o01]*m1x) * wl[ic*9+6];
      acc += (in[ic*HW + o10]*m1y) * wl[ic*9+2];
      acc += (in[ic*HW + o11]*(m1x*m1y)) * wl[ic*9+0];
    }
  }
  const int oy = 2*qy+py, ox = 2*qx+px;
  float r = (ACT==0) ? fmaxf(acc, 0.f) : 1.f/(1.f + __expf(-acc));
  out[(oc*2*Hin + oy)*2*Win + ox] = r;
}

extern "C" void kernel_launch(void* const* d_in, const int* in_sizes, int n_in,
                              void* d_out, int out_size, void* d_ws, size_t ws_size,
                              hipStream_t stream){
  const float* X    = (const float*)d_in[0];
  const float* EPS  = (const float*)d_in[1];
  const float* c1w  = (const float*)d_in[2];  const float* c1b = (const float*)d_in[3];
  const float* q1w  = (const float*)d_in[4];  const float* q1b = (const float*)d_in[5];
  const float* k1w  = (const float*)d_in[6];  const float* k1b = (const float*)d_in[7];
  const float* v1w  = (const float*)d_in[8];  const float* v1b = (const float*)d_in[9];
  const float* g1   = (const float*)d_in[10];
  const float* c2w  = (const float*)d_in[11]; const float* c2b = (const float*)d_in[12];
  const float* q2w  = (const float*)d_in[13]; const float* q2b = (const float*)d_in[14];
  const float* k2w  = (const float*)d_in[15]; const float* k2b = (const float*)d_in[16];
  const float* v2w  = (const float*)d_in[17]; const float* v2b = (const float*)d_in[18];
  const float* g2   = (const float*)d_in[19];
  const float* c3w  = (const float*)d_in[20]; const float* c3b = (const float*)d_in[21];
  const float* fmw  = (const float*)d_in[22]; const float* fmb = (const float*)d_in[23];
  const float* flw  = (const float*)d_in[24]; const float* flb = (const float*)d_in[25];
  const float* fdw  = (const float*)d_in[26]; const float* fdb = (const float*)d_in[27];
  const float* d1w  = (const float*)d_in[28]; const float* d1b = (const float*)d_in[29];
  const float* d2w  = (const float*)d_in[30]; const float* d2b = (const float*)d_in[31];
  const float* d3w  = (const float*)d_in[32]; const float* d3b = (const float*)d_in[33];

  float* ws  = (float*)d_ws;
  float* h1  = ws;            // 401408   [32][112][112]
  float* h1a = h1  + 401408;  // 401408
  float* q1  = h1a + 401408;  // 50176    [12544][4]
  float* k1  = q1  + 50176;   // 50176    [4][12544]
  float* v1f = k1  + 50176;   // 401408 slot; holds bf16 [32][12544]
  float* h2  = v1f + 401408;  // 200704   [64][56][56]
  float* h2a = h2  + 200704;  // 200704
  float* q2  = h2a + 200704;  // 25088
  float* k2  = q2  + 25088;   // 25088
  float* v2f = k2  + 25088;   // 200704 slot; holds bf16 [64][3136]
  float* h3  = v2f + 200704;  // 100352   [128][28][28]
  float* z   = h3  + 100352 + 200704;  // 256 (old plv slot tail keeps alignment)
  float* part= h3  + 100352 + 200704 + 256;  // attn partial acc region
  bf16* v1b_ = (bf16*)v1f;
  bf16* v2b_ = (bf16*)v2f;
  // fc2 partials alias the (dead-by-then) attn partial region:
  float* pmu = part;            // 200704  [256][784]
  float* plv = part + 200704;   // 200704  [256][784]
  // decoder buffers alias dead encoder regions:
  float* dd0 = h1;            // 100352 (h1 dead after attn1 combine)
  float* dd1 = h1 + 100352;   // 200704
  float* dd2 = h1a;           // 401408 (h1a dead after conv2)

  const size_t base = 2258176;                 // floats up to 'part' (unchanged from r6)
  const bool big = ws_size >= (base + 2809856 + 87808) * 4;  // NSPLIT=7 footprint
  float* pdn = part + (big ? 2809856 : 802816);

  float* OUT = (float*)d_out;   // [recon 150528 | mu 256 | logvar 256], all f32

  k_conv_s2t<3><<<dim3(49,32),dim3(256),0,stream>>>(X, c1w, c1b, h1, 224, 224);
  k_qkv<32,4,4><<<dim3(196),dim3(256),0,stream>>>(h1, q1w,q1b, k1w,k1b, v1w,v1b, q1,k1,v1b_, 12544);
  if(big){
    k_attn_mfma<32,4,128,7,2><<<dim3(686),dim3(256),0,stream>>>(q1,k1,v1b_, part, pdn, 12544);
    k_attn_comb<32,7><<<dim3(1568),dim3(256),0,stream>>>(part, pdn, h1, g1, h1a, 12544);
  } else {
    k_attn_mfma<32,4,128,2,2><<<dim3(196),dim3(256),0,stream>>>(q1,k1,v1b_, part, pdn, 12544);
    k_attn_comb<32,2><<<dim3(1568),dim3(256),0,stream>>>(part, pdn, h1, g1, h1a, 12544);
  }
  k_conv_s2t<32><<<dim3(13,64),dim3(256),0,stream>>>(h1a, c2w, c2b, h2, 112, 112);
  k_qkv<64,8,8><<<dim3(98),dim3(256),0,stream>>>(h2, q2w,q2b, k2w,k2b, v2w,v2b, q2,k2,v2b_, 3136);
  if(big){
    k_attn_mfma<64,8,64,7,1><<<dim3(343),dim3(256),0,stream>>>(q2,k2,v2b_, part, pdn, 3136);
    k_attn_comb<64,7><<<dim3(784),dim3(256),0,stream>>>(part, pdn, h2, g2, h2a, 3136);
  } else {
    k_attn_mfma<64,8,64,1,1><<<dim3(49),dim3(256),0,stream>>>(q2,k2,v2b_, part, pdn, 3136);
    k_attn_comb<64,1><<<dim3(784),dim3(256),0,stream>>>(part, pdn, h2, g2, h2a, 3136);
  }
  k_conv_s2t<64><<<dim3(4,128),dim3(256),0,stream>>>(h2a, c3w, c3b, h3, 56, 56);
  k_fc2_part<<<dim3(784),dim3(256),0,stream>>>(h3, fmw, flw, pmu, plv);
  k_reparam<<<dim3(1),dim3(256),0,stream>>>(pmu, plv, fmb, flb, EPS, z, OUT+150528, OUT+150784);
  k_fc_dec<<<dim3(392),dim3(256),0,stream>>>(z, fdw, fdb, dd0);
  k_deconv_p<128,64,0><<<dim3(13,64),dim3(256),0,stream>>>(dd0, d1w, d1b, dd1, 28,28);
  k_deconv_p<64,32,0><<<dim3(49,32),dim3(256),0,stream>>>(dd1, d2w, d2b, dd2, 56,56);
  k_deconv_p<32,3,1><<<dim3(196,3),dim3(256),0,stream>>>(dd2, d3w, d3b, OUT, 112,112);
}

// Round 9
// 378.733 us; speedup vs baseline: 3.1327x; 1.2114x over previous
//
#include <hip/hip_runtime.h>
#include <hip/hip_bf16.h>

typedef __hip_bfloat16 bf16;
typedef __attribute__((ext_vector_type(8))) short short8v;   // 8 x bf16 (4 VGPR) MFMA frag
typedef __attribute__((ext_vector_type(4))) float f32x4;

__device__ __forceinline__ unsigned int cvtpk(float lo, float hi){
  unsigned int r;
  asm volatile("v_cvt_pk_bf16_f32 %0, %1, %2" : "=v"(r) : "v"(lo), "v"(hi));
  return r;
}

// ---------- conv 3x3 stride2 pad1 + relu; per-oc block, LDS weights, branch-free ----------
template<int CIN>
__global__ __launch_bounds__(256) void k_conv_s2t(const float* __restrict__ in, const float* __restrict__ w,
    const float* __restrict__ bias, float* __restrict__ out, int Hin, int Win){
  const int Hout = Hin>>1, Wout = Win>>1, HW = Hout*Wout;
  __shared__ float wl[CIN*9];
  const int oc = blockIdx.y, tid = threadIdx.x;
  for(int i=tid;i<CIN*9;i+=256) wl[i] = w[oc*CIN*9 + i];
  __syncthreads();
  const int idx = blockIdx.x*256 + tid;
  if(idx >= HW) return;
  const int oy = idx/Wout, ox = idx - oy*Wout;
  const int iy0 = 2*oy-1, ix0 = 2*ox-1;
  const float mt = iy0>=0 ? 1.f:0.f, ml = ix0>=0 ? 1.f:0.f;
  const int iyc = iy0<0?0:iy0, ixc = ix0<0?0:ix0;
  const int x1 = ix0+1, x2 = ix0+2;
  float acc = bias[oc];
  #pragma unroll 4
  for(int ic=0; ic<CIN; ++ic){
    const float* b0 = in + (ic*Hin + iyc )*Win;
    const float* b1 = in + (ic*Hin + iy0+1)*Win;
    const float* b2 = in + (ic*Hin + iy0+2)*Win;
    const float* wp = wl + ic*9;
    float t00 = b0[ixc]*(mt*ml), t01 = b0[x1]*mt, t02 = b0[x2]*mt;
    float t10 = b1[ixc]*ml,      t11 = b1[x1],    t12 = b1[x2];
    float t20 = b2[ixc]*ml,      t21 = b2[x1],    t22 = b2[x2];
    acc += t00*wp[0]+t01*wp[1]+t02*wp[2]
         + t10*wp[3]+t11*wp[4]+t12*wp[5]
         + t20*wp[6]+t21*wp[7]+t22*wp[8];
  }
  out[oc*HW + idx] = fmaxf(acc, 0.f);
}

// ---------- q/k/v projections, TPN threads per token; v stored bf16 ----------
template<int C, int O, int TPN>
__global__ __launch_bounds__(256) void k_qkv(const float* __restrict__ x,  // [C][N]
    const float* __restrict__ wq, const float* __restrict__ bq,
    const float* __restrict__ wk, const float* __restrict__ bk,
    const float* __restrict__ wv, const float* __restrict__ bv,
    float* __restrict__ q, float* __restrict__ k, bf16* __restrict__ v, int N){
  constexpr int NPB = 256/TPN;
  constexpr int OP = O/TPN > 0 ? O/TPN : 1;
  constexpr int CP = C/TPN;
  const int n = blockIdx.x*NPB + threadIdx.x/TPN;
  const int p = threadIdx.x%TPN;
  float xc[C];
  #pragma unroll
  for(int c=0;c<C;++c) xc[c] = x[c*N+n];
  #pragma unroll
  for(int oo=0;oo<OP;++oo){
    int o = p*OP + oo;
    float aq = bq[o], ak = bk[o];
    #pragma unroll
    for(int c=0;c<C;++c){ aq += wq[o*C+c]*xc[c]; ak += wk[o*C+c]*xc[c]; }
    q[n*O+o] = aq;
    k[o*N+n] = ak;
  }
  #pragma unroll
  for(int cc=0;cc<CP;++cc){
    int o = p*CP + cc;
    float av = bv[o];
    #pragma unroll
    for(int c=0;c<C;++c) av += wv[o*C+c]*xc[c];
    v[o*N+n] = __float2bfloat16(av);
  }
}

// ---------- MFMA flash attention, partial (key-split), QG query-groups/wave ----------
template<int C, int O, int ST, int NSPLIT, int QG>
__global__ __launch_bounds__(256) void k_attn_mfma(
    const float* __restrict__ q, const float* __restrict__ kk, const bf16* __restrict__ vb,
    float* __restrict__ pacc, float* __restrict__ pden, int N){
  constexpr int NT = C/16;
  constexpr int OF4 = O/4;
  constexpr int VROW = ST*2 + 16;        // bytes
  __shared__ __align__(16) char vsm[C*VROW];
  __shared__ float4 ksm4[(ST + ST/8)*OF4];
  const int tid = threadIdx.x;
  const int qblk = blockIdx.x / NSPLIT, split = blockIdx.x % NSPLIT;
  const int KEYS = N / NSPLIT;
  const int kbase = split * KEYS;
  const int wv = tid >> 6;
  const int l  = tid & 63;
  const int lg = l >> 4, lq = l & 15;
  const int qbase = qblk*(64*QG) + wv*(16*QG);
  float qv[QG][O];
  #pragma unroll
  for(int g=0; g<QG; ++g)
    #pragma unroll
    for(int o=0;o<O;++o) qv[g][o] = q[(qbase + g*16 + lq)*O + o];
  f32x4 acc[QG][NT];
  #pragma unroll
  for(int g=0; g<QG; ++g)
    #pragma unroll
    for(int nt=0;nt<NT;++nt) acc[g][nt] = (f32x4){0.f,0.f,0.f,0.f};
  float den[QG];
  #pragma unroll
  for(int g=0; g<QG; ++g) den[g] = 0.f;

  for(int g0=0; g0<KEYS; g0+=ST){
    __syncthreads();
    for(int j=tid; j<ST; j+=256){
      int row = j + (j>>3);
      #pragma unroll
      for(int h=0;h<OF4;++h){
        float4 kv;
        ((float*)&kv)[0] = kk[(h*4+0)*N + kbase + g0 + j];
        ((float*)&kv)[1] = kk[(h*4+1)*N + kbase + g0 + j];
        ((float*)&kv)[2] = kk[(h*4+2)*N + kbase + g0 + j];
        ((float*)&kv)[3] = kk[(h*4+3)*N + kbase + g0 + j];
        ksm4[row*OF4 + h] = kv;
      }
    }
    for(int ch=tid; ch < C*(ST/8); ch += 256){
      int c = ch / (ST/8), j8 = ch % (ST/8);
      *(uint4*)(vsm + c*VROW + j8*16) =
          *(const uint4*)(vb + (size_t)c*N + kbase + g0 + j8*8);
    }
    __syncthreads();
    #pragma unroll
    for(int s=0; s<ST/32; ++s){
      float pr[QG][8];
      #pragma unroll
      for(int e=0; e<8; ++e){
        const int row = s*36 + lg*9 + e;
        #pragma unroll
        for(int g=0; g<QG; ++g){
          float sc = 0.f;
          #pragma unroll
          for(int h=0;h<OF4;++h){
            float4 k4 = ksm4[row*OF4 + h];
            sc += qv[g][h*4+0]*k4.x + qv[g][h*4+1]*k4.y + qv[g][h*4+2]*k4.z + qv[g][h*4+3]*k4.w;
          }
          pr[g][e] = __expf(sc);
        }
      }
      union { unsigned int u[4]; short8v s8; } pa[QG];
      #pragma unroll
      for(int g=0; g<QG; ++g){
        #pragma unroll
        for(int u=0; u<4; ++u) pa[g].u[u] = cvtpk(pr[g][2*u], pr[g][2*u+1]);
        #pragma unroll
        for(int e=0; e<8; ++e) den[g] += pr[g][e];
      }
      #pragma unroll
      for(int nt=0; nt<NT; ++nt){
        short8v bf_ = *(const short8v*)(vsm + (lq + nt*16)*VROW + (s*32 + lg*8)*2);
        #pragma unroll
        for(int g=0; g<QG; ++g)
          acc[g][nt] = __builtin_amdgcn_mfma_f32_16x16x32_bf16(pa[g].s8, bf_, acc[g][nt], 0,0,0);
      }
    }
  }
  #pragma unroll
  for(int g=0; g<QG; ++g){
    den[g] += __shfl_xor(den[g], 16);
    den[g] += __shfl_xor(den[g], 32);
    if(lg == 0) pden[(size_t)split*N + qbase + g*16 + lq] = den[g];
  }
  #pragma unroll
  for(int g=0; g<QG; ++g)
    #pragma unroll
    for(int nt=0; nt<NT; ++nt)
      #pragma unroll
      for(int r=0;r<4;++r){
        int qg_ = qbase + g*16 + lg*4 + r;
        pacc[((size_t)split*N + qg_)*C + nt*16 + lq] = acc[g][nt][r];
      }
}

// ---------- attention combine ----------
template<int C, int NSPLIT>
__global__ __launch_bounds__(256) void k_attn_comb(const float* __restrict__ pacc, const float* __restrict__ pden,
    const float* __restrict__ xin, const float* __restrict__ gamma, float* __restrict__ out, int N){
  int idx = blockIdx.x*256 + threadIdx.x;
  if(idx >= N*C) return;
  int c = idx / N, m = idx - c*N;
  float a = 0.f, d = 0.f;
  #pragma unroll
  for(int s=0;s<NSPLIT;++s){
    a += pacc[((size_t)s*N + m)*C + c];
    d += pden[(size_t)s*N + m];
  }
  out[idx] = gamma[0]*a/d + xin[idx];
}

// ---------- fc_mu / fc_lv partials: wave-row float4 streaming ----------
// Block = 128-row chunk; wave w owns rows w*32..+31; a 256-float row = 64 lanes x float4
// (coalesced 1KB). 64 independent loads/thread. Cross-wave LDS reduce; coalesced
// partial write pmu[blk*256 + o].
__global__ __launch_bounds__(256) void k_fc2_part(const float* __restrict__ hf,
    const float* __restrict__ wmu, const float* __restrict__ wlv,
    float* __restrict__ pmu, float* __restrict__ plv){
  __shared__ float sh[128];
  __shared__ float4 redm[4][64];
  __shared__ float4 redl[4][64];
  const int t = threadIdx.x, blk = blockIdx.x, f0 = blk*128;
  const int w = t>>6, l = t&63;
  if(t < 128) sh[t] = hf[f0+t];
  __syncthreads();
  const float4* wm = (const float4*)(wmu + (size_t)(f0 + w*32)*256) + l;
  const float4* wv_ = (const float4*)(wlv + (size_t)(f0 + w*32)*256) + l;
  f32x4 am = {0.f,0.f,0.f,0.f}, al = {0.f,0.f,0.f,0.f};
  #pragma unroll 8
  for(int r=0; r<32; ++r){
    float h = sh[w*32 + r];
    float4 a = wm[r*64];
    float4 b = wv_[r*64];
    am[0] += h*a.x; am[1] += h*a.y; am[2] += h*a.z; am[3] += h*a.w;
    al[0] += h*b.x; al[1] += h*b.y; al[2] += h*b.z; al[3] += h*b.w;
  }
  redm[w][l] = (float4){am[0],am[1],am[2],am[3]};
  redl[w][l] = (float4){al[0],al[1],al[2],al[3]};
  __syncthreads();
  const float* rm = (const float*)redm;
  const float* rl = (const float*)redl;
  float mu = rm[t] + rm[256+t] + rm[512+t] + rm[768+t];
  float lv = rl[t] + rl[256+t] + rl[512+t] + rl[768+t];
  pmu[(size_t)blk*256 + t] = mu;
  plv[(size_t)blk*256 + t] = lv;
}

// ---------- reduce partials + reparametrize; block-per-output ----------
__global__ __launch_bounds__(256) void k_reparam_p(const float* __restrict__ pmu, const float* __restrict__ plv,
    const float* __restrict__ bmu, const float* __restrict__ blv, const float* __restrict__ eps,
    float* __restrict__ z, float* __restrict__ omu, float* __restrict__ olv){
  const int o = blockIdx.x, t = threadIdx.x;
  __shared__ float rm[4], rl[4];
  float sm = 0.f, sl = 0.f;
  for(int j=t; j<784; j+=256){ sm += pmu[(size_t)j*256+o]; sl += plv[(size_t)j*256+o]; }
  #pragma unroll
  for(int off=32; off>=1; off>>=1){ sm += __shfl_xor(sm, off); sl += __shfl_xor(sl, off); }
  if((t&63)==0){ rm[t>>6]=sm; rl[t>>6]=sl; }
  __syncthreads();
  if(t==0){
    float mu = bmu[o] + rm[0]+rm[1]+rm[2]+rm[3];
    float lv = blv[o] + rl[0]+rl[1]+rl[2]+rl[3];
    z[o] = mu + eps[o] * expf(0.5f*lv);
    omu[o] = mu;
    olv[o] = lv;
  }
}

// ---------- decoder fc partials: blockIdx.y = o-split (64 o's each) ----------
__global__ __launch_bounds__(256) void k_fc_dec_p(const float* __restrict__ z, const float* __restrict__ w,
    float* __restrict__ pfd){
  __shared__ float sz[64];
  const int t = threadIdx.x, blk = blockIdx.x, os = blockIdx.y;
  if(t<64) sz[t] = z[os*64 + t];
  __syncthreads();
  const size_t f4 = (size_t)blk*256 + t;        // float4 index into 25088
  const float4* wp = (const float4*)w + (size_t)os*64*25088 + f4;
  f32x4 a = {0.f,0.f,0.f,0.f};
  #pragma unroll 8
  for(int o=0;o<64;++o){
    float zz = sz[o];
    float4 u = wp[(size_t)o*25088];
    a[0] += zz*u.x; a[1] += zz*u.y; a[2] += zz*u.z; a[3] += zz*u.w;
  }
  ((float4*)pfd)[(size_t)os*25088 + f4] = (float4){a[0],a[1],a[2],a[3]};
}

// ---------- decoder fc combine: relu(sum partials + bias) ----------
__global__ __launch_bounds__(256) void k_fc_dec_c(const float* __restrict__ pfd, const float* __restrict__ b,
    float* __restrict__ out){
  const int i = blockIdx.x*256 + threadIdx.x;   // float4 index
  const float4* p4 = (const float4*)pfd;
  float4 s0 = p4[i], s1 = p4[25088+i], s2 = p4[2*25088+i], s3 = p4[3*25088+i];
  float4 bb = ((const float4*)b)[i];
  float4 r;
  r.x = fmaxf(s0.x+s1.x+s2.x+s3.x+bb.x, 0.f);
  r.y = fmaxf(s0.y+s1.y+s2.y+s3.y+bb.y, 0.f);
  r.z = fmaxf(s0.z+s1.z+s2.z+s3.z+bb.z, 0.f);
  r.w = fmaxf(s0.w+s1.w+s2.w+s3.w+bb.w, 0.f);
  ((float4*)out)[i] = r;
}

// ---------- transposed conv 3x3 s2 p1 op1, parity-decomposed ----------
template<int CIN, int COUT, int ACT>
__global__ __launch_bounds__(256) void k_deconv_p(const float* __restrict__ in, const float* __restrict__ w,
    const float* __restrict__ bias, float* __restrict__ out, int Hin, int Win){
  __shared__ float wl[CIN*9];
  const int oc = blockIdx.y;
  const int tid = threadIdx.x;
  for(int i=tid; i<CIN*9; i+=256) wl[i] = w[((i/9)*COUT + oc)*9 + (i%9)];
  __syncthreads();
  const int nq = Hin*Win;
  const int code = blockIdx.x*256 + tid;
  if(code >= 4*nq) return;
  const int q = code % nq;
  const int pcode = code / nq;
  const int px = pcode & 1, py = pcode >> 1;
  const int qy = q / Win, qx = q - qy*Win;
  const float m1x = (qx+1 < Win) ? 1.f : 0.f;
  const float m1y = (qy+1 < Hin) ? 1.f : 0.f;
  const int qxc = (qx+1 < Win) ? qx+1 : qx;
  const int qyc = (qy+1 < Hin) ? qy+1 : qy;
  const int o00 = qy*Win+qx, o01 = qy*Win+qxc, o10 = qyc*Win+qx, o11 = qyc*Win+qxc;
  const int HW = nq;
  float acc = bias[oc];
  if(pcode == 0){
    #pragma unroll 4
    for(int ic=0; ic<CIN; ++ic) acc += in[ic*HW + o00] * wl[ic*9+4];
  } else if(pcode == 1){
    #pragma unroll 4
    for(int ic=0; ic<CIN; ++ic){
      acc += in[ic*HW + o00] * wl[ic*9+5];
      acc += (in[ic*HW + o01]*m1x) * wl[ic*9+3];
    }
  } else if(pcode == 2){
    #pragma unroll 4
    for(int ic=0; ic<CIN; ++ic){
      acc += in[ic*HW + o00] * wl[ic*9+7];
      acc += (in[ic*HW + o10]*m1y) * wl[ic*9+1];
    }
  } else {
    #pragma unroll 4
    for(int ic=0; ic<CIN; ++ic){
      acc += in[ic*HW + o00] * wl[ic*9+8];
      acc += (in[ic*HW + o01]*m1x) * wl[ic*9+6];
      acc += (in[ic*HW + o10]*m1y) * wl[ic*9+2];
      acc += (in[ic*HW + o11]*(m1x*m1y)) * wl[ic*9+0];
    }
  }
  const int oy = 2*qy+py, ox = 2*qx+px;
  float r = (ACT==0) ? fmaxf(acc, 0.f) : 1.f/(1.f + __expf(-acc));
  out[(oc*2*Hin + oy)*2*Win + ox] = r;
}

extern "C" void kernel_launch(void* const* d_in, const int* in_sizes, int n_in,
                              void* d_out, int out_size, void* d_ws, size_t ws_size,
                              hipStream_t stream){
  const float* X    = (const float*)d_in[0];
  const float* EPS  = (const float*)d_in[1];
  const float* c1w  = (const float*)d_in[2];  const float* c1b = (const float*)d_in[3];
  const float* q1w  = (const float*)d_in[4];  const float* q1b = (const float*)d_in[5];
  const float* k1w  = (const float*)d_in[6];  const float* k1b = (const float*)d_in[7];
  const float* v1w  = (const float*)d_in[8];  const float* v1b = (const float*)d_in[9];
  const float* g1   = (const float*)d_in[10];
  const float* c2w  = (const float*)d_in[11]; const float* c2b = (const float*)d_in[12];
  const float* q2w  = (const float*)d_in[13]; const float* q2b = (const float*)d_in[14];
  const float* k2w  = (const float*)d_in[15]; const float* k2b = (const float*)d_in[16];
  const float* v2w  = (const float*)d_in[17]; const float* v2b = (const float*)d_in[18];
  const float* g2   = (const float*)d_in[19];
  const float* c3w  = (const float*)d_in[20]; const float* c3b = (const float*)d_in[21];
  const float* fmw  = (const float*)d_in[22]; const float* fmb = (const float*)d_in[23];
  const float* flw  = (const float*)d_in[24]; const float* flb = (const float*)d_in[25];
  const float* fdw  = (const float*)d_in[26]; const float* fdb = (const float*)d_in[27];
  const float* d1w  = (const float*)d_in[28]; const float* d1b = (const float*)d_in[29];
  const float* d2w  = (const float*)d_in[30]; const float* d2b = (const float*)d_in[31];
  const float* d3w  = (const float*)d_in[32]; const float* d3b = (const float*)d_in[33];

  float* ws  = (float*)d_ws;
  float* h1  = ws;            // 401408   [32][112][112]
  float* h1a = h1  + 401408;  // 401408
  float* q1  = h1a + 401408;  // 50176
  float* k1  = q1  + 50176;   // 50176
  float* v1f = k1  + 50176;   // 401408 slot; bf16 [32][12544]
  float* h2  = v1f + 401408;  // 200704
  float* h2a = h2  + 200704;  // 200704
  float* q2  = h2a + 200704;  // 25088
  float* k2  = q2  + 25088;   // 25088
  float* v2f = k2  + 25088;   // 200704 slot; bf16 [64][3136]
  float* h3  = v2f + 200704;  // 100352
  float* z   = h3  + 100352 + 200704;  // 256
  float* part= h3  + 100352 + 200704 + 256;  // attn partial region
  bf16* v1b_ = (bf16*)v1f;
  bf16* v2b_ = (bf16*)v2f;
  // fc partials alias the (dead-by-then) attn partial region:
  float* pmu = part;              // 200704  [784][256]
  float* plv = part + 200704;     // 200704  [784][256]
  float* pfd = part + 401408;     // 401408  [4][100352]
  // decoder buffers alias dead encoder regions:
  float* dd0 = h1;            // 100352
  float* dd1 = h1 + 100352;   // 200704
  float* dd2 = h1a;           // 401408

  const size_t base = 2258176;
  const bool big = ws_size >= (base + 2809856 + 87808) * 4;  // NSPLIT=7 footprint
  float* pdn = part + (big ? 2809856 : 802816);

  float* OUT = (float*)d_out;   // [recon 150528 | mu 256 | logvar 256], all f32

  k_conv_s2t<3><<<dim3(49,32),dim3(256),0,stream>>>(X, c1w, c1b, h1, 224, 224);
  k_qkv<32,4,4><<<dim3(196),dim3(256),0,stream>>>(h1, q1w,q1b, k1w,k1b, v1w,v1b, q1,k1,v1b_, 12544);
  if(big){
    k_attn_mfma<32,4,128,7,2><<<dim3(686),dim3(256),0,stream>>>(q1,k1,v1b_, part, pdn, 12544);
    k_attn_comb<32,7><<<dim3(1568),dim3(256),0,stream>>>(part, pdn, h1, g1, h1a, 12544);
  } else {
    k_attn_mfma<32,4,128,2,2><<<dim3(196),dim3(256),0,stream>>>(q1,k1,v1b_, part, pdn, 12544);
    k_attn_comb<32,2><<<dim3(1568),dim3(256),0,stream>>>(part, pdn, h1, g1, h1a, 12544);
  }
  k_conv_s2t<32><<<dim3(13,64),dim3(256),0,stream>>>(h1a, c2w, c2b, h2, 112, 112);
  k_qkv<64,8,8><<<dim3(98),dim3(256),0,stream>>>(h2, q2w,q2b, k2w,k2b, v2w,v2b, q2,k2,v2b_, 3136);
  if(big){
    k_attn_mfma<64,8,64,7,1><<<dim3(343),dim3(256),0,stream>>>(q2,k2,v2b_, part, pdn, 3136);
    k_attn_comb<64,7><<<dim3(784),dim3(256),0,stream>>>(part, pdn, h2, g2, h2a, 3136);
  } else {
    k_attn_mfma<64,8,64,1,1><<<dim3(49),dim3(256),0,stream>>>(q2,k2,v2b_, part, pdn, 3136);
    k_attn_comb<64,1><<<dim3(784),dim3(256),0,stream>>>(part, pdn, h2, g2, h2a, 3136);
  }
  k_conv_s2t<64><<<dim3(4,128),dim3(256),0,stream>>>(h2a, c3w, c3b, h3, 56, 56);
  k_fc2_part<<<dim3(784),dim3(256),0,stream>>>(h3, fmw, flw, pmu, plv);
  k_reparam_p<<<dim3(256),dim3(256),0,stream>>>(pmu, plv, fmb, flb, EPS, z, OUT+150528, OUT+150784);
  k_fc_dec_p<<<dim3(98,4),dim3(256),0,stream>>>(z, fdw, pfd);
  k_fc_dec_c<<<dim3(98),dim3(256),0,stream>>>(pfd, fdb, dd0);
  k_deconv_p<128,64,0><<<dim3(13,64),dim3(256),0,stream>>>(dd0, d1w, d1b, dd1, 28,28);
  k_deconv_p<64,32,0><<<dim3(49,32),dim3(256),0,stream>>>(dd1, d2w, d2b, dd2, 56,56);
  k_deconv_p<32,3,1><<<dim3(196,3),dim3(256),0,stream>>>(dd2, d3w, d3b, OUT, 112,112);
}